// Round 1
// baseline (1146.357 us; speedup 1.0000x reference)
//
#include <hip/hip_runtime.h>

typedef short   short8  __attribute__((ext_vector_type(8)));
typedef unsigned short ushort8 __attribute__((ext_vector_type(8)));
typedef float   floatx4 __attribute__((ext_vector_type(4)));

__device__ __forceinline__ float bf2f(unsigned short h) {
    unsigned int u = ((unsigned int)h) << 16;
    return __builtin_bit_cast(float, u);
}
__device__ __forceinline__ unsigned short f2bf(float f) {
    unsigned int u = __builtin_bit_cast(unsigned int, f);
    u += 0x7fffu + ((u >> 16) & 1u);   // round-to-nearest-even
    return (unsigned short)(u >> 16);
}

// ---------------- dtype detection ----------------
// flags[0] != 0  =>  float tensors delivered as fp32 (else bf16)
// flags[1] != 0  =>  edge_index delivered as int32 (else int64)

__global__ __launch_bounds__(256) void k_detect_f32(const unsigned short* __restrict__ X,
                                                    int nPairs, int* __restrict__ flags) {
    int i = blockIdx.x * 256 + threadIdx.x;
    if (i < nPairs) {
        unsigned short w = X[2 * i];
        if ((w & 0x7F80u) == 0x7F80u) atomicOr(&flags[0], 1);
    }
}

__global__ __launch_bounds__(256) void k_detect_i32(const int* __restrict__ ei,
                                                    int E, int* __restrict__ flags) {
    int i = blockIdx.x * 256 + threadIdx.x;
    if (i < E) {
        if (ei[2 * i + 1] != 0) atomicOr(&flags[1], 1);
    }
}

// ---------------- small converters ----------------

__global__ __launch_bounds__(256) void k_cvt_f32(const void* __restrict__ in,
                                                 float* __restrict__ out, int n,
                                                 const int* __restrict__ flags) {
    int i = blockIdx.x * 256 + threadIdx.x;
    if (i < n)
        out[i] = flags[0] ? ((const float*)in)[i] : bf2f(((const unsigned short*)in)[i]);
}

__global__ __launch_bounds__(256) void k_tcvt(const void* __restrict__ in,
                                              unsigned short* __restrict__ out,
                                              int R, int C, const int* __restrict__ flags) {
    int idx = blockIdx.x * 256 + threadIdx.x;
    if (idx >= R * C) return;
    int r = idx / C, c = idx - r * C;
    unsigned short v = flags[0] ? f2bf(((const float*)in)[idx])
                                : ((const unsigned short*)in)[idx];
    out[(long)c * R + r] = v;
}

// ---------------- graph setup ----------------

__global__ __launch_bounds__(256) void k_count(const int* __restrict__ ei, int E, int n,
                                               const int* __restrict__ flags,
                                               int* __restrict__ deg) {
    int e = blockIdx.x * 256 + threadIdx.x;
    if (e >= E) return;
    int sh = (flags[1] == 0) ? 1 : 0;           // int64 -> stride-2 words
    int d = ei[(long)(E + e) << sh];
    if ((unsigned)d < (unsigned)n) atomicAdd(&deg[d], 1);
}

__global__ __launch_bounds__(256) void k_dinv(const int* __restrict__ deg,
                                              float* __restrict__ dinv, int n) {
    int i = blockIdx.x * 256 + threadIdx.x;
    if (i < n) dinv[i] = rsqrtf((float)(deg[i] + 1));  // +1 self-loop
}

__global__ __launch_bounds__(1024) void k_scan(const int* __restrict__ deg,
                                               int* __restrict__ row_start,
                                               int* __restrict__ cursor, int n) {
    __shared__ int sums[1024];
    int t = threadIdx.x;
    int CH = (n + 1 + 1023) / 1024;
    int base = t * CH;
    int s = 0;
    for (int i = 0; i < CH; i++) {
        int idx = base + i;
        if (idx < n) s += deg[idx];
    }
    sums[t] = s;
    __syncthreads();
    for (int off = 1; off < 1024; off <<= 1) {
        int v = (t >= off) ? sums[t - off] : 0;
        __syncthreads();
        if (t >= off) sums[t] += v;
        __syncthreads();
    }
    int run = (t > 0) ? sums[t - 1] : 0;
    for (int i = 0; i < CH; i++) {
        int idx = base + i;
        if (idx < n) {
            row_start[idx] = run;
            cursor[idx] = run;
            run += deg[idx];
        } else if (idx == n) {
            row_start[n] = run;
        }
    }
}

__global__ __launch_bounds__(256) void k_fill(const int* __restrict__ ei, int E, int n,
                                              const int* __restrict__ flags,
                                              int* __restrict__ cursor,
                                              int* __restrict__ csr) {
    int e = blockIdx.x * 256 + threadIdx.x;
    if (e >= E) return;
    int sh = (flags[1] == 0) ? 1 : 0;
    int s = ei[(long)e << sh];
    int d = ei[(long)(E + e) << sh];
    if ((unsigned)d >= (unsigned)n || (unsigned)s >= (unsigned)n) return;
    int p = atomicAdd(&cursor[d], 1);
    csr[p] = s;
}

// ---------------- NT GEMM: C[M,N] = A[M,K] * Bt[N,K]^T (+bias), fp32 acc ------

__device__ __forceinline__ ushort8 ld8(const void* p, long e, bool f32) {
    if (!f32) return *(const ushort8*)((const unsigned short*)p + e);
    const float* f = (const float*)p + e;
    ushort8 r;
#pragma unroll
    for (int i = 0; i < 8; i++) r[i] = f2bf(f[i]);
    return r;
}

// BN template: 128 for wide outputs (fewer A re-reads), 64 for N=128 GEMMs.
// XCD swizzle: blocks sharing an A row-panel must land on the SAME XCD's L2
// (default round-robin puts each panel-mate on a different XCD -> 8-16x A fetch).
template <int BN>
__global__ __launch_bounds__(256) void gemm_nt(const void* __restrict__ A, int aMaybeF32,
                                               const void* __restrict__ Bt, int bMaybeF32,
                                               void* __restrict__ Cv, long coff,
                                               const float* __restrict__ bias,
                                               int M, int N, int K, int finalOut,
                                               const int* __restrict__ flags) {
    constexpr int BM = 128, BK = 32, LDT = 40;  // pad 32->40: only free 2-way conflicts
    constexpr int JR = BN / 16;                 // B fragments per wave
    __shared__ unsigned short sA[BM * LDT];
    __shared__ unsigned short sB[BN * LDT];
    const bool af32 = aMaybeF32 && flags[0];
    const bool bf32 = bMaybeF32 && flags[0];
    const bool of32 = finalOut && flags[0];
    const bool hasb = bias != nullptr;
    const int t = threadIdx.x;

    // bijective XCD-aware swizzle (contiguous x-major chunk per XCD)
    const int GX = gridDim.x;
    const int nwg = GX * gridDim.y;
    const int orig = blockIdx.y * GX + blockIdx.x;
    const int q8 = nwg >> 3, r8 = nwg & 7;
    const int xcd = orig & 7, cidx = orig >> 3;
    const int swz = (xcd < r8 ? xcd * (q8 + 1) : r8 * (q8 + 1) + (xcd - r8) * q8) + cidx;
    const int m0 = (swz / GX) * BM;
    const int n0 = (swz % GX) * BN;

    const int w = t >> 6;
    const int lane = t & 63;
    const int id = lane & 15;
    const int q = lane >> 4;

    floatx4 acc[2][JR];
    for (int s = 0; s < 2; s++)
        for (int j = 0; j < JR; j++) acc[s][j] = (floatx4)0.0f;

    const int ar = t >> 2;          // 0..63
    const int ac = (t & 3) * 8;     // 0,8,16,24

    for (int k0 = 0; k0 < K; k0 += BK) {
        long r0 = min(m0 + ar, M - 1);
        long r1 = min(m0 + ar + 64, M - 1);
        ushort8 va0 = ld8(A, r0 * K + k0 + ac, af32);
        ushort8 va1 = ld8(A, r1 * K + k0 + ac, af32);
        ushort8 vb0, vb1;
        vb0 = ld8(Bt, (long)min(n0 + ar, N - 1) * K + k0 + ac, bf32);
        if (BN == 128)
            vb1 = ld8(Bt, (long)min(n0 + ar + 64, N - 1) * K + k0 + ac, bf32);
        __syncthreads();
        *(ushort8*)(sA + ar * LDT + ac) = va0;
        *(ushort8*)(sA + (ar + 64) * LDT + ac) = va1;
        *(ushort8*)(sB + ar * LDT + ac) = vb0;
        if (BN == 128)
            *(ushort8*)(sB + (ar + 64) * LDT + ac) = vb1;
        __syncthreads();

        short8 afrag[2], bfrag[JR];
        for (int s = 0; s < 2; s++)
            afrag[s] = *(const short8*)(sA + (32 * w + 16 * s + id) * LDT + q * 8);
        for (int j = 0; j < JR; j++)
            bfrag[j] = *(const short8*)(sB + (16 * j + id) * LDT + q * 8);
        for (int s = 0; s < 2; s++)
            for (int j = 0; j < JR; j++)
                acc[s][j] = __builtin_amdgcn_mfma_f32_16x16x32_bf16(
                    afrag[s], bfrag[j], acc[s][j], 0, 0, 0);
    }

    for (int s = 0; s < 2; s++)
        for (int j = 0; j < JR; j++) {
            int col = n0 + 16 * j + id;                        // C/D: col=lane&15
            float bv = hasb ? bias[col] : 0.0f;
            for (int r = 0; r < 4; r++) {
                int row = m0 + 32 * w + 16 * s + q * 4 + r;    // row=(lane>>4)*4+reg
                if (row < M) {
                    float v = acc[s][j][r] + bv;
                    if (of32) ((float*)Cv)[coff + (long)row * N + col] = v;
                    else ((unsigned short*)Cv)[coff + (long)row * N + col] = f2bf(v);
                }
            }
        }
}

// ------- aggregation: O[i] = dinv[i]*(sum_j T[csr_j]*dinv[csr_j] + T[i]*dinv[i]) + b

template <int D>
__global__ __launch_bounds__(256) void k_agg(const unsigned short* __restrict__ T,
                                             const int* __restrict__ rs,
                                             const int* __restrict__ csr,
                                             const float* __restrict__ dinv,
                                             const float* __restrict__ bias,
                                             unsigned short* __restrict__ O, int n) {
    constexpr int TPN = D / 8;
    constexpr int NPB = 256 / TPN;
    int lt = threadIdx.x % TPN;
    int node = blockIdx.x * NPB + threadIdx.x / TPN;
    if (node >= n) return;
    int off = lt * 8;
    float acc[8];
#pragma unroll
    for (int i = 0; i < 8; i++) acc[i] = 0.0f;
    int beg = rs[node], end = rs[node + 1];
    for (int j = beg; j < end; j++) {
        int s = csr[j];
        if ((unsigned)s >= (unsigned)n) continue;
        float wgt = dinv[s];
        ushort8 v = *(const ushort8*)(T + (long)s * D + off);
#pragma unroll
        for (int i = 0; i < 8; i++) acc[i] += wgt * bf2f(v[i]);
    }
    float di = dinv[node];
    ushort8 sv = *(const ushort8*)(T + (long)node * D + off);
    ushort8 o;
#pragma unroll
    for (int i = 0; i < 8; i++) {
        float r = di * (acc[i] + di * bf2f(sv[i])) + (bias ? bias[off + i] : 0.0f);
        o[i] = f2bf(r);
    }
    *(ushort8*)(O + (long)node * D + off) = o;
}

// ---------------- final copy of z, h2 into d_out ----------------

__global__ __launch_bounds__(256) void k_out(const unsigned short* __restrict__ z,
                                             const unsigned short* __restrict__ h2,
                                             void* __restrict__ out, int nOut,
                                             const int* __restrict__ flags) {
    int i = blockIdx.x * 256 + threadIdx.x;
    if (i >= 2 * nOut) return;
    unsigned short v = (i < nOut) ? z[i] : h2[i - nOut];
    if (flags[0]) ((float*)out)[i] = bf2f(v);
    else ((unsigned short*)out)[i] = v;
}

// ---------------- launch ----------------

extern "C" void kernel_launch(void* const* d_in, const int* in_sizes, int n_in,
                              void* d_out, int out_size, void* d_ws, size_t ws_size,
                              hipStream_t stream) {
    const int IN  = in_sizes[7];           // 1024
    const int HID = in_sizes[3];           // 512
    const int OUT = in_sizes[5];           // 128
    const int Nn  = in_sizes[0] / IN;      // 20000
    const int E   = in_sizes[1] / 2;       // 160000

    const void* X   = d_in[0];
    const int*  ei  = (const int*)d_in[1];
    const void* W1  = d_in[2];
    const void* b1  = d_in[3];
    const void* W2  = d_in[4];
    const void* b2  = d_in[5];
    const void* b3  = d_in[6];
    const void* b4  = d_in[7];
    const void* Hd1 = d_in[8];

    char* base = (char*)d_ws;
    size_t o = 0;
    auto carve = [&](size_t bytes) -> char* {
        char* p = base + o;
        o = (o + bytes + 255) & ~(size_t)255;
        return p;
    };
    int*   flags  = (int*)carve(2 * 4);
    int*   deg    = (int*)carve((size_t)Nn * 4);
    int*   rowst  = (int*)carve((size_t)(Nn + 1) * 4);
    int*   cursor = (int*)carve((size_t)Nn * 4);
    float* dinv   = (float*)carve((size_t)Nn * 4);
    int*   csr    = (int*)carve((size_t)E * 4);
    float* biasf  = (float*)carve((size_t)(HID + OUT + HID + IN) * 4);
    float* bc1 = biasf, *bc2 = biasf + HID, *bc3 = biasf + HID + OUT,
         *bc4 = biasf + HID + OUT + HID;
    unsigned short* W1t  = (unsigned short*)carve((size_t)IN * HID * 2);
    unsigned short* W2t  = (unsigned short*)carve((size_t)HID * OUT * 2);
    unsigned short* H1t  = (unsigned short*)carve((size_t)OUT * OUT * 2);
    unsigned short* t1   = (unsigned short*)carve((size_t)Nn * HID * 2); // also g4
    unsigned short* h1   = (unsigned short*)carve((size_t)Nn * HID * 2);
    unsigned short* h3   = (unsigned short*)carve((size_t)Nn * HID * 2);
    unsigned short* t2   = (unsigned short*)carve((size_t)Nn * OUT * 2); // also g3
    unsigned short* h2ws = (unsigned short*)carve((size_t)Nn * OUT * 2);
    unsigned short* zws  = (unsigned short*)carve((size_t)Nn * OUT * 2);

    // --- detection + graph setup ---
    hipMemsetAsync(flags, 0, 8, stream);
    hipMemsetAsync(deg, 0, (size_t)Nn * 4, stream);
    int nPairs = 1 << 20;
    k_detect_f32<<<(nPairs + 255) / 256, 256, 0, stream>>>((const unsigned short*)X, nPairs, flags);
    k_detect_i32<<<(E + 255) / 256, 256, 0, stream>>>(ei, E, flags);

    k_cvt_f32<<<(HID + 255) / 256, 256, 0, stream>>>(b1, bc1, HID, flags);
    k_cvt_f32<<<(OUT + 255) / 256, 256, 0, stream>>>(b2, bc2, OUT, flags);
    k_cvt_f32<<<(HID + 255) / 256, 256, 0, stream>>>(b3, bc3, HID, flags);
    k_cvt_f32<<<(IN + 255) / 256, 256, 0, stream>>>(b4, bc4, IN, flags);

    k_tcvt<<<(HID * IN + 255) / 256, 256, 0, stream>>>(W1, W1t, HID, IN, flags);
    k_tcvt<<<(OUT * HID + 255) / 256, 256, 0, stream>>>(W2, W2t, OUT, HID, flags);
    k_tcvt<<<(OUT * OUT + 255) / 256, 256, 0, stream>>>(Hd1, H1t, OUT, OUT, flags);

    k_count<<<(E + 255) / 256, 256, 0, stream>>>(ei, E, Nn, flags, deg);
    k_dinv<<<(Nn + 255) / 256, 256, 0, stream>>>(deg, dinv, Nn);
    k_scan<<<1, 1024, 0, stream>>>(deg, rowst, cursor, Nn);
    k_fill<<<(E + 255) / 256, 256, 0, stream>>>(ei, E, Nn, flags, cursor, csr);

    dim3 blk(256);
    auto ggrid = [&](int Ncols, int bn) { return dim3((Ncols + bn - 1) / bn, (Nn + 127) / 128); };
    const long zOff = 0, h2Off = (long)Nn * OUT, h4Off = (long)Nn * OUT * 2;

    // conv1: t1 = X @ W1^T ; h1 = S*t1 + b1
    gemm_nt<128><<<ggrid(HID, 128), blk, 0, stream>>>(X, 1, W1, 1, t1, 0, nullptr, Nn, HID, IN, 0, flags);
    k_agg<512><<<(Nn * 64 + 255) / 256, blk, 0, stream>>>(t1, rowst, csr, dinv, bc1, h1, Nn);

    // conv2: t2 = h1 @ W2^T ; h2 = S*t2 + b2
    gemm_nt<64><<<ggrid(OUT, 64), blk, 0, stream>>>(h1, 0, W2, 1, t2, 0, nullptr, Nn, OUT, HID, 0, flags);
    k_agg<128><<<(Nn * 16 + 255) / 256, blk, 0, stream>>>(t2, rowst, csr, dinv, bc2, h2ws, Nn);

    // z = h2 @ head1
    gemm_nt<64><<<ggrid(OUT, 64), blk, 0, stream>>>(h2ws, 0, H1t, 0, zws, 0, nullptr, Nn, OUT, OUT, 0, flags);

    // conv3 (agg-first, tied W2^T): g3 = S*z ; h3 = g3 @ W2 + b3
    k_agg<128><<<(Nn * 16 + 255) / 256, blk, 0, stream>>>(zws, rowst, csr, dinv, nullptr, t2, Nn);
    gemm_nt<128><<<ggrid(HID, 128), blk, 0, stream>>>(t2, 0, W2t, 0, h3, 0, bc3, Nn, HID, OUT, 0, flags);

    // conv4 (agg-first, tied W1^T): g4 = S*h3 ; h4 = g4 @ W1 + b4 -> d_out
    k_agg<512><<<(Nn * 64 + 255) / 256, blk, 0, stream>>>(h3, rowst, csr, dinv, nullptr, t1, Nn);
    gemm_nt<128><<<ggrid(IN, 128), blk, 0, stream>>>(t1, 0, W1t, 0, d_out, h4Off, bc4, Nn, IN, HID, 1, flags);

    // z, h2 -> d_out
    k_out<<<(2 * (int)h2Off + 255) / 256, blk, 0, stream>>>(zws, h2ws, d_out, (int)h2Off, flags);
}

// Round 2
// 601.236 us; speedup vs baseline: 1.9067x; 1.9067x over previous
//
#include <hip/hip_runtime.h>

typedef short   short8  __attribute__((ext_vector_type(8)));
typedef unsigned short ushort8 __attribute__((ext_vector_type(8)));
typedef float   floatx4 __attribute__((ext_vector_type(4)));

__device__ __forceinline__ float bf2f(unsigned short h) {
    unsigned int u = ((unsigned int)h) << 16;
    return __builtin_bit_cast(float, u);
}
__device__ __forceinline__ unsigned short f2bf(float f) {
    unsigned int u = __builtin_bit_cast(unsigned int, f);
    u += 0x7fffu + ((u >> 16) & 1u);   // round-to-nearest-even
    return (unsigned short)(u >> 16);
}

// ---------------- dtype detection ----------------
// flags[0] != 0  =>  float tensors delivered as fp32 (else bf16)
// flags[1] != 0  =>  edge_index delivered as int32 (else int64)

__global__ __launch_bounds__(256) void k_detect_f32(const unsigned short* __restrict__ X,
                                                    int nPairs, int* __restrict__ flags) {
    int i = blockIdx.x * 256 + threadIdx.x;
    if (i < nPairs) {
        unsigned short w = X[2 * i];
        if ((w & 0x7F80u) == 0x7F80u) atomicOr(&flags[0], 1);
    }
}

__global__ __launch_bounds__(256) void k_detect_i32(const int* __restrict__ ei,
                                                    int E, int* __restrict__ flags) {
    int i = blockIdx.x * 256 + threadIdx.x;
    if (i < E) {
        if (ei[2 * i + 1] != 0) atomicOr(&flags[1], 1);
    }
}

// ---------------- small converters ----------------

__global__ __launch_bounds__(256) void k_cvt_f32(const void* __restrict__ in,
                                                 float* __restrict__ out, int n,
                                                 const int* __restrict__ flags) {
    int i = blockIdx.x * 256 + threadIdx.x;
    if (i < n)
        out[i] = flags[0] ? ((const float*)in)[i] : bf2f(((const unsigned short*)in)[i]);
}

__global__ __launch_bounds__(256) void k_tcvt(const void* __restrict__ in,
                                              unsigned short* __restrict__ out,
                                              int R, int C, const int* __restrict__ flags) {
    int idx = blockIdx.x * 256 + threadIdx.x;
    if (idx >= R * C) return;
    int r = idx / C, c = idx - r * C;
    unsigned short v = flags[0] ? f2bf(((const float*)in)[idx])
                                : ((const unsigned short*)in)[idx];
    out[(long)c * R + r] = v;
}

// ---------------- graph setup ----------------

__global__ __launch_bounds__(256) void k_count(const int* __restrict__ ei, int E, int n,
                                               const int* __restrict__ flags,
                                               int* __restrict__ deg) {
    int e = blockIdx.x * 256 + threadIdx.x;
    if (e >= E) return;
    int sh = (flags[1] == 0) ? 1 : 0;           // int64 -> stride-2 words
    int d = ei[(long)(E + e) << sh];
    if ((unsigned)d < (unsigned)n) atomicAdd(&deg[d], 1);
}

__global__ __launch_bounds__(256) void k_dinv(const int* __restrict__ deg,
                                              float* __restrict__ dinv, int n) {
    int i = blockIdx.x * 256 + threadIdx.x;
    if (i < n) dinv[i] = rsqrtf((float)(deg[i] + 1));  // +1 self-loop
}

__global__ __launch_bounds__(1024) void k_scan(const int* __restrict__ deg,
                                               int* __restrict__ row_start,
                                               int* __restrict__ cursor, int n) {
    __shared__ int sums[1024];
    int t = threadIdx.x;
    int CH = (n + 1 + 1023) / 1024;
    int base = t * CH;
    int s = 0;
    for (int i = 0; i < CH; i++) {
        int idx = base + i;
        if (idx < n) s += deg[idx];
    }
    sums[t] = s;
    __syncthreads();
    for (int off = 1; off < 1024; off <<= 1) {
        int v = (t >= off) ? sums[t - off] : 0;
        __syncthreads();
        if (t >= off) sums[t] += v;
        __syncthreads();
    }
    int run = (t > 0) ? sums[t - 1] : 0;
    for (int i = 0; i < CH; i++) {
        int idx = base + i;
        if (idx < n) {
            row_start[idx] = run;
            cursor[idx] = run;
            run += deg[idx];
        } else if (idx == n) {
            row_start[n] = run;
        }
    }
}

__global__ __launch_bounds__(256) void k_fill(const int* __restrict__ ei, int E, int n,
                                              const int* __restrict__ flags,
                                              int* __restrict__ cursor,
                                              int* __restrict__ csr) {
    int e = blockIdx.x * 256 + threadIdx.x;
    if (e >= E) return;
    int sh = (flags[1] == 0) ? 1 : 0;
    int s = ei[(long)e << sh];
    int d = ei[(long)(E + e) << sh];
    if ((unsigned)d >= (unsigned)n || (unsigned)s >= (unsigned)n) return;
    int p = atomicAdd(&cursor[d], 1);
    csr[p] = s;
}

// ---------------- NT GEMM: C[M,N] = A[M,K] * Bt[N,K]^T (+bias), fp32 acc ------

__device__ __forceinline__ ushort8 ld8(const void* p, long e, bool f32) {
    if (!f32) return *(const ushort8*)((const unsigned short*)p + e);
    const float* f = (const float*)p + e;
    ushort8 r;
#pragma unroll
    for (int i = 0; i < 8; i++) r[i] = f2bf(f[i]);
    return r;
}

// BN template: 128 for wide outputs (fewer A re-reads), 64 for N=128 GEMMs.
// XCD swizzle: blocks sharing an A row-panel must land on the SAME XCD's L2
// (default round-robin puts each panel-mate on a different XCD -> 8-16x A fetch).
// NOTE (round-1 post-mortem): all acc/frag loops MUST be #pragma unroll'd.
// With JR=8 clang left them rolled -> acc[s][j] runtime-indexed -> scratch
// (1.24 GB spill writes measured, 4x slowdown). Rule #20.
template <int BN>
__global__ __launch_bounds__(256, 2) void gemm_nt(const void* __restrict__ A, int aMaybeF32,
                                               const void* __restrict__ Bt, int bMaybeF32,
                                               void* __restrict__ Cv, long coff,
                                               const float* __restrict__ bias,
                                               int M, int N, int K, int finalOut,
                                               const int* __restrict__ flags) {
    constexpr int BM = 128, BK = 32, LDT = 40;  // pad 32->40: only free 2-way conflicts
    constexpr int JR = BN / 16;                 // B fragments per wave
    __shared__ unsigned short sA[BM * LDT];
    __shared__ unsigned short sB[BN * LDT];
    const bool af32 = aMaybeF32 && flags[0];
    const bool bf32 = bMaybeF32 && flags[0];
    const bool of32 = finalOut && flags[0];
    const bool hasb = bias != nullptr;
    const int t = threadIdx.x;

    // bijective XCD-aware swizzle (contiguous x-major chunk per XCD)
    const int GX = gridDim.x;
    const int nwg = GX * gridDim.y;
    const int orig = blockIdx.y * GX + blockIdx.x;
    const int q8 = nwg >> 3, r8 = nwg & 7;
    const int xcd = orig & 7, cidx = orig >> 3;
    const int swz = (xcd < r8 ? xcd * (q8 + 1) : r8 * (q8 + 1) + (xcd - r8) * q8) + cidx;
    const int m0 = (swz / GX) * BM;
    const int n0 = (swz % GX) * BN;

    const int w = t >> 6;
    const int lane = t & 63;
    const int id = lane & 15;
    const int q = lane >> 4;

    floatx4 acc[2][JR];
#pragma unroll
    for (int s = 0; s < 2; s++)
#pragma unroll
        for (int j = 0; j < JR; j++) acc[s][j] = (floatx4)0.0f;

    const int ar = t >> 2;          // 0..63
    const int ac = (t & 3) * 8;     // 0,8,16,24

    for (int k0 = 0; k0 < K; k0 += BK) {
        long r0 = min(m0 + ar, M - 1);
        long r1 = min(m0 + ar + 64, M - 1);
        ushort8 va0 = ld8(A, r0 * K + k0 + ac, af32);
        ushort8 va1 = ld8(A, r1 * K + k0 + ac, af32);
        ushort8 vb0, vb1;
        vb0 = ld8(Bt, (long)min(n0 + ar, N - 1) * K + k0 + ac, bf32);
        if (BN == 128)
            vb1 = ld8(Bt, (long)min(n0 + ar + 64, N - 1) * K + k0 + ac, bf32);
        __syncthreads();
        *(ushort8*)(sA + ar * LDT + ac) = va0;
        *(ushort8*)(sA + (ar + 64) * LDT + ac) = va1;
        *(ushort8*)(sB + ar * LDT + ac) = vb0;
        if (BN == 128)
            *(ushort8*)(sB + (ar + 64) * LDT + ac) = vb1;
        __syncthreads();

        short8 afrag[2], bfrag[JR];
#pragma unroll
        for (int s = 0; s < 2; s++)
            afrag[s] = *(const short8*)(sA + (32 * w + 16 * s + id) * LDT + q * 8);
#pragma unroll
        for (int j = 0; j < JR; j++)
            bfrag[j] = *(const short8*)(sB + (16 * j + id) * LDT + q * 8);
#pragma unroll
        for (int s = 0; s < 2; s++)
#pragma unroll
            for (int j = 0; j < JR; j++)
                acc[s][j] = __builtin_amdgcn_mfma_f32_16x16x32_bf16(
                    afrag[s], bfrag[j], acc[s][j], 0, 0, 0);
    }

#pragma unroll
    for (int s = 0; s < 2; s++)
#pragma unroll
        for (int j = 0; j < JR; j++) {
            int col = n0 + 16 * j + id;                        // C/D: col=lane&15
            float bv = hasb ? bias[col] : 0.0f;
#pragma unroll
            for (int r = 0; r < 4; r++) {
                int row = m0 + 32 * w + 16 * s + q * 4 + r;    // row=(lane>>4)*4+reg
                if (row < M) {
                    float v = acc[s][j][r] + bv;
                    if (of32) ((float*)Cv)[coff + (long)row * N + col] = v;
                    else ((unsigned short*)Cv)[coff + (long)row * N + col] = f2bf(v);
                }
            }
        }
}

// ------- aggregation: O[i] = dinv[i]*(sum_j T[csr_j]*dinv[csr_j] + T[i]*dinv[i]) + b

template <int D>
__global__ __launch_bounds__(256) void k_agg(const unsigned short* __restrict__ T,
                                             const int* __restrict__ rs,
                                             const int* __restrict__ csr,
                                             const float* __restrict__ dinv,
                                             const float* __restrict__ bias,
                                             unsigned short* __restrict__ O, int n) {
    constexpr int TPN = D / 8;
    constexpr int NPB = 256 / TPN;
    int lt = threadIdx.x % TPN;
    int node = blockIdx.x * NPB + threadIdx.x / TPN;
    if (node >= n) return;
    int off = lt * 8;
    float acc[8];
#pragma unroll
    for (int i = 0; i < 8; i++) acc[i] = 0.0f;
    int beg = rs[node], end = rs[node + 1];
    for (int j = beg; j < end; j++) {
        int s = csr[j];
        if ((unsigned)s >= (unsigned)n) continue;
        float wgt = dinv[s];
        ushort8 v = *(const ushort8*)(T + (long)s * D + off);
#pragma unroll
        for (int i = 0; i < 8; i++) acc[i] += wgt * bf2f(v[i]);
    }
    float di = dinv[node];
    ushort8 sv = *(const ushort8*)(T + (long)node * D + off);
    ushort8 o;
#pragma unroll
    for (int i = 0; i < 8; i++) {
        float r = di * (acc[i] + di * bf2f(sv[i])) + (bias ? bias[off + i] : 0.0f);
        o[i] = f2bf(r);
    }
    *(ushort8*)(O + (long)node * D + off) = o;
}

// ---------------- final copy of z, h2 into d_out ----------------

__global__ __launch_bounds__(256) void k_out(const unsigned short* __restrict__ z,
                                             const unsigned short* __restrict__ h2,
                                             void* __restrict__ out, int nOut,
                                             const int* __restrict__ flags) {
    int i = blockIdx.x * 256 + threadIdx.x;
    if (i >= 2 * nOut) return;
    unsigned short v = (i < nOut) ? z[i] : h2[i - nOut];
    if (flags[0]) ((float*)out)[i] = bf2f(v);
    else ((unsigned short*)out)[i] = v;
}

// ---------------- launch ----------------

extern "C" void kernel_launch(void* const* d_in, const int* in_sizes, int n_in,
                              void* d_out, int out_size, void* d_ws, size_t ws_size,
                              hipStream_t stream) {
    const int IN  = in_sizes[7];           // 1024
    const int HID = in_sizes[3];           // 512
    const int OUT = in_sizes[5];           // 128
    const int Nn  = in_sizes[0] / IN;      // 20000
    const int E   = in_sizes[1] / 2;       // 160000

    const void* X   = d_in[0];
    const int*  ei  = (const int*)d_in[1];
    const void* W1  = d_in[2];
    const void* b1  = d_in[3];
    const void* W2  = d_in[4];
    const void* b2  = d_in[5];
    const void* b3  = d_in[6];
    const void* b4  = d_in[7];
    const void* Hd1 = d_in[8];

    char* base = (char*)d_ws;
    size_t o = 0;
    auto carve = [&](size_t bytes) -> char* {
        char* p = base + o;
        o = (o + bytes + 255) & ~(size_t)255;
        return p;
    };
    int*   flags  = (int*)carve(2 * 4);
    int*   deg    = (int*)carve((size_t)Nn * 4);
    int*   rowst  = (int*)carve((size_t)(Nn + 1) * 4);
    int*   cursor = (int*)carve((size_t)Nn * 4);
    float* dinv   = (float*)carve((size_t)Nn * 4);
    int*   csr    = (int*)carve((size_t)E * 4);
    float* biasf  = (float*)carve((size_t)(HID + OUT + HID + IN) * 4);
    float* bc1 = biasf, *bc2 = biasf + HID, *bc3 = biasf + HID + OUT,
         *bc4 = biasf + HID + OUT + HID;
    unsigned short* W1t  = (unsigned short*)carve((size_t)IN * HID * 2);
    unsigned short* W2t  = (unsigned short*)carve((size_t)HID * OUT * 2);
    unsigned short* H1t  = (unsigned short*)carve((size_t)OUT * OUT * 2);
    unsigned short* t1   = (unsigned short*)carve((size_t)Nn * HID * 2); // also g4
    unsigned short* h1   = (unsigned short*)carve((size_t)Nn * HID * 2);
    unsigned short* h3   = (unsigned short*)carve((size_t)Nn * HID * 2);
    unsigned short* t2   = (unsigned short*)carve((size_t)Nn * OUT * 2); // also g3
    unsigned short* h2ws = (unsigned short*)carve((size_t)Nn * OUT * 2);
    unsigned short* zws  = (unsigned short*)carve((size_t)Nn * OUT * 2);

    // --- detection + graph setup ---
    hipMemsetAsync(flags, 0, 8, stream);
    hipMemsetAsync(deg, 0, (size_t)Nn * 4, stream);
    int nPairs = 1 << 20;
    k_detect_f32<<<(nPairs + 255) / 256, 256, 0, stream>>>((const unsigned short*)X, nPairs, flags);
    k_detect_i32<<<(E + 255) / 256, 256, 0, stream>>>(ei, E, flags);

    k_cvt_f32<<<(HID + 255) / 256, 256, 0, stream>>>(b1, bc1, HID, flags);
    k_cvt_f32<<<(OUT + 255) / 256, 256, 0, stream>>>(b2, bc2, OUT, flags);
    k_cvt_f32<<<(HID + 255) / 256, 256, 0, stream>>>(b3, bc3, HID, flags);
    k_cvt_f32<<<(IN + 255) / 256, 256, 0, stream>>>(b4, bc4, IN, flags);

    k_tcvt<<<(HID * IN + 255) / 256, 256, 0, stream>>>(W1, W1t, HID, IN, flags);
    k_tcvt<<<(OUT * HID + 255) / 256, 256, 0, stream>>>(W2, W2t, OUT, HID, flags);
    k_tcvt<<<(OUT * OUT + 255) / 256, 256, 0, stream>>>(Hd1, H1t, OUT, OUT, flags);

    k_count<<<(E + 255) / 256, 256, 0, stream>>>(ei, E, Nn, flags, deg);
    k_dinv<<<(Nn + 255) / 256, 256, 0, stream>>>(deg, dinv, Nn);
    k_scan<<<1, 1024, 0, stream>>>(deg, rowst, cursor, Nn);
    k_fill<<<(E + 255) / 256, 256, 0, stream>>>(ei, E, Nn, flags, cursor, csr);

    dim3 blk(256);
    auto ggrid = [&](int Ncols, int bn) { return dim3((Ncols + bn - 1) / bn, (Nn + 127) / 128); };
    const long zOff = 0, h2Off = (long)Nn * OUT, h4Off = (long)Nn * OUT * 2;

    // conv1: t1 = X @ W1^T ; h1 = S*t1 + b1
    gemm_nt<128><<<ggrid(HID, 128), blk, 0, stream>>>(X, 1, W1, 1, t1, 0, nullptr, Nn, HID, IN, 0, flags);
    k_agg<512><<<(Nn * 64 + 255) / 256, blk, 0, stream>>>(t1, rowst, csr, dinv, bc1, h1, Nn);

    // conv2: t2 = h1 @ W2^T ; h2 = S*t2 + b2
    gemm_nt<64><<<ggrid(OUT, 64), blk, 0, stream>>>(h1, 0, W2, 1, t2, 0, nullptr, Nn, OUT, HID, 0, flags);
    k_agg<128><<<(Nn * 16 + 255) / 256, blk, 0, stream>>>(t2, rowst, csr, dinv, bc2, h2ws, Nn);

    // z = h2 @ head1
    gemm_nt<64><<<ggrid(OUT, 64), blk, 0, stream>>>(h2ws, 0, H1t, 0, zws, 0, nullptr, Nn, OUT, OUT, 0, flags);

    // conv3 (agg-first, tied W2^T): g3 = S*z ; h3 = g3 @ W2 + b3
    k_agg<128><<<(Nn * 16 + 255) / 256, blk, 0, stream>>>(zws, rowst, csr, dinv, nullptr, t2, Nn);
    gemm_nt<128><<<ggrid(HID, 128), blk, 0, stream>>>(t2, 0, W2t, 0, h3, 0, bc3, Nn, HID, OUT, 0, flags);

    // conv4 (agg-first, tied W1^T): g4 = S*h3 ; h4 = g4 @ W1 + b4 -> d_out
    k_agg<512><<<(Nn * 64 + 255) / 256, blk, 0, stream>>>(h3, rowst, csr, dinv, nullptr, t1, Nn);
    gemm_nt<128><<<ggrid(IN, 128), blk, 0, stream>>>(t1, 0, W1t, 0, d_out, h4Off, bc4, Nn, IN, HID, 1, flags);

    // z, h2 -> d_out
    k_out<<<(2 * (int)h2Off + 255) / 256, blk, 0, stream>>>(zws, h2ws, d_out, (int)h2Off, flags);
}

// Round 3
// 572.633 us; speedup vs baseline: 2.0019x; 1.0500x over previous
//
#include <hip/hip_runtime.h>

typedef short   short8  __attribute__((ext_vector_type(8)));
typedef unsigned short ushort8 __attribute__((ext_vector_type(8)));
typedef float   floatx4 __attribute__((ext_vector_type(4)));

__device__ __forceinline__ float bf2f(unsigned short h) {
    unsigned int u = ((unsigned int)h) << 16;
    return __builtin_bit_cast(float, u);
}
__device__ __forceinline__ unsigned short f2bf(float f) {
    unsigned int u = __builtin_bit_cast(unsigned int, f);
    u += 0x7fffu + ((u >> 16) & 1u);   // round-to-nearest-even
    return (unsigned short)(u >> 16);
}

// ---------------- dtype detection ----------------
// flags[0] != 0  =>  float tensors delivered as fp32 (else bf16)
// flags[1] != 0  =>  edge_index delivered as int32 (else int64)

__global__ __launch_bounds__(256) void k_detect_f32(const unsigned short* __restrict__ X,
                                                    int nPairs, int* __restrict__ flags) {
    int i = blockIdx.x * 256 + threadIdx.x;
    if (i < nPairs) {
        unsigned short w = X[2 * i];
        if ((w & 0x7F80u) == 0x7F80u) atomicOr(&flags[0], 1);
    }
}

__global__ __launch_bounds__(256) void k_detect_i32(const int* __restrict__ ei,
                                                    int E, int* __restrict__ flags) {
    int i = blockIdx.x * 256 + threadIdx.x;
    if (i < E) {
        if (ei[2 * i + 1] != 0) atomicOr(&flags[1], 1);
    }
}

// ---------------- small converters ----------------

__global__ __launch_bounds__(256) void k_cvt_f32(const void* __restrict__ in,
                                                 float* __restrict__ out, int n,
                                                 const int* __restrict__ flags) {
    int i = blockIdx.x * 256 + threadIdx.x;
    if (i < n)
        out[i] = flags[0] ? ((const float*)in)[i] : bf2f(((const unsigned short*)in)[i]);
}

// bulk convert (or passthrough-copy) to bf16, 8 elems/thread, coalesced.
// Round-2 post-mortem: fp32 inputs fed directly to gemm_nt cost 16 scalar
// loads + 16 f2bf per thread per K-step (4-8x transaction amplification,
// conv1 = 105us latency-bound). Converting once up front is ~25us.
__global__ __launch_bounds__(256) void k_cvt8(const void* __restrict__ in,
                                              unsigned short* __restrict__ out,
                                              long n8, const int* __restrict__ flags) {
    long i = (long)blockIdx.x * 256 + threadIdx.x;
    if (i >= n8) return;
    ushort8 o;
    if (flags[0]) {
        const floatx4* f = (const floatx4*)in + i * 2;
        floatx4 a = f[0], b = f[1];
#pragma unroll
        for (int j = 0; j < 4; j++) { o[j] = f2bf(a[j]); o[4 + j] = f2bf(b[j]); }
    } else {
        o = *((const ushort8*)in + i);
    }
    *((ushort8*)out + i) = o;
}

__global__ __launch_bounds__(256) void k_tcvt(const void* __restrict__ in,
                                              unsigned short* __restrict__ out,
                                              int R, int C, const int* __restrict__ flags) {
    int idx = blockIdx.x * 256 + threadIdx.x;
    if (idx >= R * C) return;
    int r = idx / C, c = idx - r * C;
    unsigned short v = flags[0] ? f2bf(((const float*)in)[idx])
                                : ((const unsigned short*)in)[idx];
    out[(long)c * R + r] = v;
}

// ---------------- graph setup ----------------

__global__ __launch_bounds__(256) void k_count(const int* __restrict__ ei, int E, int n,
                                               const int* __restrict__ flags,
                                               int* __restrict__ deg) {
    int e = blockIdx.x * 256 + threadIdx.x;
    if (e >= E) return;
    int sh = (flags[1] == 0) ? 1 : 0;           // int64 -> stride-2 words
    int d = ei[(long)(E + e) << sh];
    if ((unsigned)d < (unsigned)n) atomicAdd(&deg[d], 1);
}

__global__ __launch_bounds__(256) void k_dinv(const int* __restrict__ deg,
                                              float* __restrict__ dinv, int n) {
    int i = blockIdx.x * 256 + threadIdx.x;
    if (i < n) dinv[i] = rsqrtf((float)(deg[i] + 1));  // +1 self-loop
}

__global__ __launch_bounds__(1024) void k_scan(const int* __restrict__ deg,
                                               int* __restrict__ row_start,
                                               int* __restrict__ cursor, int n) {
    __shared__ int sums[1024];
    int t = threadIdx.x;
    int CH = (n + 1 + 1023) / 1024;
    int base = t * CH;
    int s = 0;
    for (int i = 0; i < CH; i++) {
        int idx = base + i;
        if (idx < n) s += deg[idx];
    }
    sums[t] = s;
    __syncthreads();
    for (int off = 1; off < 1024; off <<= 1) {
        int v = (t >= off) ? sums[t - off] : 0;
        __syncthreads();
        if (t >= off) sums[t] += v;
        __syncthreads();
    }
    int run = (t > 0) ? sums[t - 1] : 0;
    for (int i = 0; i < CH; i++) {
        int idx = base + i;
        if (idx < n) {
            row_start[idx] = run;
            cursor[idx] = run;
            run += deg[idx];
        } else if (idx == n) {
            row_start[n] = run;
        }
    }
}

__global__ __launch_bounds__(256) void k_fill(const int* __restrict__ ei, int E, int n,
                                              const int* __restrict__ flags,
                                              int* __restrict__ cursor,
                                              int* __restrict__ csr) {
    int e = blockIdx.x * 256 + threadIdx.x;
    if (e >= E) return;
    int sh = (flags[1] == 0) ? 1 : 0;
    int s = ei[(long)e << sh];
    int d = ei[(long)(E + e) << sh];
    if ((unsigned)d >= (unsigned)n || (unsigned)s >= (unsigned)n) return;
    int p = atomicAdd(&cursor[d], 1);
    csr[p] = s;
}

// ---------------- NT GEMM: C[M,N] = A[M,K] * Bt[N,K]^T (+bias), fp32 acc ------
// A, Bt always bf16 (pre-converted). Output bf16, or fp32 if finalOut&&flags[0].
// BN template: 64 for N=512 GEMMs (grid 1256 -> 4.9 blk/CU, latency hiding),
// 128 for N=1024 (conv4, already 1256 blocks).
// XCD swizzle: blocks sharing an A row-panel must land on the SAME XCD's L2.
// NOTE (round-1 post-mortem): all acc/frag loops MUST be #pragma unroll'd
// (rolled JR-loop -> runtime-indexed acc -> scratch spill, 1.24 GB writes).

template <int BN>
__global__ __launch_bounds__(256, 3) void gemm_nt(const unsigned short* __restrict__ A,
                                               const unsigned short* __restrict__ Bt,
                                               void* __restrict__ Cv, long coff,
                                               const float* __restrict__ bias,
                                               int M, int N, int K, int finalOut,
                                               const int* __restrict__ flags) {
    constexpr int BM = 128, BK = 32, LDT = 40;  // pad 32->40: only free 2-way conflicts
    constexpr int JR = BN / 16;                 // B fragments per wave
    __shared__ unsigned short sA[BM * LDT];
    __shared__ unsigned short sB[BN * LDT];
    const bool of32 = finalOut && flags[0];
    const bool hasb = bias != nullptr;
    const int t = threadIdx.x;

    // bijective XCD-aware swizzle (contiguous chunk per XCD)
    const int GX = gridDim.x;
    const int nwg = GX * gridDim.y;
    const int orig = blockIdx.y * GX + blockIdx.x;
    const int q8 = nwg >> 3, r8 = nwg & 7;
    const int xcd = orig & 7, cidx = orig >> 3;
    const int swz = (xcd < r8 ? xcd * (q8 + 1) : r8 * (q8 + 1) + (xcd - r8) * q8) + cidx;
    const int m0 = (swz / GX) * BM;
    const int n0 = (swz % GX) * BN;

    const int w = t >> 6;
    const int lane = t & 63;
    const int id = lane & 15;
    const int q = lane >> 4;

    floatx4 acc[2][JR];
#pragma unroll
    for (int s = 0; s < 2; s++)
#pragma unroll
        for (int j = 0; j < JR; j++) acc[s][j] = (floatx4)0.0f;

    const int ar = t >> 2;          // 0..63
    const int ac = (t & 3) * 8;     // 0,8,16,24

    for (int k0 = 0; k0 < K; k0 += BK) {
        long r0 = min(m0 + ar, M - 1);
        long r1 = min(m0 + ar + 64, M - 1);
        ushort8 va0 = *(const ushort8*)(A + r0 * K + k0 + ac);
        ushort8 va1 = *(const ushort8*)(A + r1 * K + k0 + ac);
        ushort8 vb0, vb1;
        vb0 = *(const ushort8*)(Bt + (long)min(n0 + ar, N - 1) * K + k0 + ac);
        if (BN == 128)
            vb1 = *(const ushort8*)(Bt + (long)min(n0 + ar + 64, N - 1) * K + k0 + ac);
        __syncthreads();
        *(ushort8*)(sA + ar * LDT + ac) = va0;
        *(ushort8*)(sA + (ar + 64) * LDT + ac) = va1;
        if (BN == 128) {
            *(ushort8*)(sB + ar * LDT + ac) = vb0;
            *(ushort8*)(sB + (ar + 64) * LDT + ac) = vb1;
        } else {
            // only first 2 waves carry B rows (64 rows total)
            if (ar < 64) *(ushort8*)(sB + ar * LDT + ac) = vb0;
        }
        __syncthreads();

        short8 afrag[2], bfrag[JR];
#pragma unroll
        for (int s = 0; s < 2; s++)
            afrag[s] = *(const short8*)(sA + (32 * w + 16 * s + id) * LDT + q * 8);
#pragma unroll
        for (int j = 0; j < JR; j++)
            bfrag[j] = *(const short8*)(sB + (16 * j + id) * LDT + q * 8);
#pragma unroll
        for (int s = 0; s < 2; s++)
#pragma unroll
            for (int j = 0; j < JR; j++)
                acc[s][j] = __builtin_amdgcn_mfma_f32_16x16x32_bf16(
                    afrag[s], bfrag[j], acc[s][j], 0, 0, 0);
    }

#pragma unroll
    for (int s = 0; s < 2; s++)
#pragma unroll
        for (int j = 0; j < JR; j++) {
            int col = n0 + 16 * j + id;                        // C/D: col=lane&15
            float bv = hasb ? bias[col] : 0.0f;
#pragma unroll
            for (int r = 0; r < 4; r++) {
                int row = m0 + 32 * w + 16 * s + q * 4 + r;    // row=(lane>>4)*4+reg
                if (row < M) {
                    float v = acc[s][j][r] + bv;
                    if (of32) ((float*)Cv)[coff + (long)row * N + col] = v;
                    else ((unsigned short*)Cv)[coff + (long)row * N + col] = f2bf(v);
                }
            }
        }
}

// ------- aggregation: O[i] = dinv[i]*(sum_j T[csr_j]*dinv[csr_j] + T[i]*dinv[i]) + b

template <int D>
__global__ __launch_bounds__(256) void k_agg(const unsigned short* __restrict__ T,
                                             const int* __restrict__ rs,
                                             const int* __restrict__ csr,
                                             const float* __restrict__ dinv,
                                             const float* __restrict__ bias,
                                             unsigned short* __restrict__ O, int n) {
    constexpr int TPN = D / 8;
    constexpr int NPB = 256 / TPN;
    int lt = threadIdx.x % TPN;
    int node = blockIdx.x * NPB + threadIdx.x / TPN;
    if (node >= n) return;
    int off = lt * 8;
    float acc[8];
#pragma unroll
    for (int i = 0; i < 8; i++) acc[i] = 0.0f;
    int beg = rs[node], end = rs[node + 1];
    for (int j = beg; j < end; j++) {
        int s = csr[j];
        if ((unsigned)s >= (unsigned)n) continue;
        float wgt = dinv[s];
        ushort8 v = *(const ushort8*)(T + (long)s * D + off);
#pragma unroll
        for (int i = 0; i < 8; i++) acc[i] += wgt * bf2f(v[i]);
    }
    float di = dinv[node];
    ushort8 sv = *(const ushort8*)(T + (long)node * D + off);
    ushort8 o;
#pragma unroll
    for (int i = 0; i < 8; i++) {
        float r = di * (acc[i] + di * bf2f(sv[i])) + (bias ? bias[off + i] : 0.0f);
        o[i] = f2bf(r);
    }
    *(ushort8*)(O + (long)node * D + off) = o;
}

// ---------------- final copy of z, h2 into d_out ----------------

__global__ __launch_bounds__(256) void k_out(const unsigned short* __restrict__ z,
                                             const unsigned short* __restrict__ h2,
                                             void* __restrict__ out, int nOut,
                                             const int* __restrict__ flags) {
    int i = blockIdx.x * 256 + threadIdx.x;
    if (i >= 2 * nOut) return;
    unsigned short v = (i < nOut) ? z[i] : h2[i - nOut];
    if (flags[0]) ((float*)out)[i] = bf2f(v);
    else ((unsigned short*)out)[i] = v;
}

// ---------------- launch ----------------

extern "C" void kernel_launch(void* const* d_in, const int* in_sizes, int n_in,
                              void* d_out, int out_size, void* d_ws, size_t ws_size,
                              hipStream_t stream) {
    const int IN  = in_sizes[7];           // 1024
    const int HID = in_sizes[3];           // 512
    const int OUT = in_sizes[5];           // 128
    const int Nn  = in_sizes[0] / IN;      // 20000
    const int E   = in_sizes[1] / 2;       // 160000

    const void* X   = d_in[0];
    const int*  ei  = (const int*)d_in[1];
    const void* W1  = d_in[2];
    const void* b1  = d_in[3];
    const void* W2  = d_in[4];
    const void* b2  = d_in[5];
    const void* b3  = d_in[6];
    const void* b4  = d_in[7];
    const void* Hd1 = d_in[8];

    char* base = (char*)d_ws;
    size_t o = 0;
    auto carve = [&](size_t bytes) -> char* {
        char* p = base + o;
        o = (o + bytes + 255) & ~(size_t)255;
        return p;
    };
    int*   flags  = (int*)carve(2 * 4);
    int*   deg    = (int*)carve((size_t)Nn * 4);
    int*   rowst  = (int*)carve((size_t)(Nn + 1) * 4);
    int*   cursor = (int*)carve((size_t)Nn * 4);
    float* dinv   = (float*)carve((size_t)Nn * 4);
    int*   csr    = (int*)carve((size_t)E * 4);
    float* biasf  = (float*)carve((size_t)(HID + OUT + HID + IN) * 4);
    float* bc1 = biasf, *bc2 = biasf + HID, *bc3 = biasf + HID + OUT,
         *bc4 = biasf + HID + OUT + HID;
    unsigned short* W1t  = (unsigned short*)carve((size_t)IN * HID * 2);
    unsigned short* W2t  = (unsigned short*)carve((size_t)HID * OUT * 2);
    unsigned short* H1t  = (unsigned short*)carve((size_t)OUT * OUT * 2);
    unsigned short* W1c  = (unsigned short*)carve((size_t)HID * IN * 2);
    unsigned short* W2c  = (unsigned short*)carve((size_t)OUT * HID * 2);
    unsigned short* Xb   = (unsigned short*)carve((size_t)Nn * IN * 2);
    unsigned short* t1   = (unsigned short*)carve((size_t)Nn * HID * 2); // also g4
    unsigned short* h1   = (unsigned short*)carve((size_t)Nn * HID * 2);
    unsigned short* h3   = (unsigned short*)carve((size_t)Nn * HID * 2);
    unsigned short* t2   = (unsigned short*)carve((size_t)Nn * OUT * 2); // also g3
    unsigned short* h2ws = (unsigned short*)carve((size_t)Nn * OUT * 2);
    unsigned short* zws  = (unsigned short*)carve((size_t)Nn * OUT * 2);

    // --- detection + graph setup ---
    hipMemsetAsync(flags, 0, 8, stream);
    hipMemsetAsync(deg, 0, (size_t)Nn * 4, stream);
    int nPairs = 1 << 20;
    k_detect_f32<<<(nPairs + 255) / 256, 256, 0, stream>>>((const unsigned short*)X, nPairs, flags);
    k_detect_i32<<<(E + 255) / 256, 256, 0, stream>>>(ei, E, flags);

    k_cvt_f32<<<(HID + 255) / 256, 256, 0, stream>>>(b1, bc1, HID, flags);
    k_cvt_f32<<<(OUT + 255) / 256, 256, 0, stream>>>(b2, bc2, OUT, flags);
    k_cvt_f32<<<(HID + 255) / 256, 256, 0, stream>>>(b3, bc3, HID, flags);
    k_cvt_f32<<<(IN + 255) / 256, 256, 0, stream>>>(b4, bc4, IN, flags);

    k_tcvt<<<(HID * IN + 255) / 256, 256, 0, stream>>>(W1, W1t, HID, IN, flags);
    k_tcvt<<<(OUT * HID + 255) / 256, 256, 0, stream>>>(W2, W2t, OUT, HID, flags);
    k_tcvt<<<(OUT * OUT + 255) / 256, 256, 0, stream>>>(Hd1, H1t, OUT, OUT, flags);

    // bf16 copies of X, W1, W2 for the GEMMs (pure-bf16 load path)
    {
        long n8x = (long)Nn * IN / 8;
        k_cvt8<<<(int)((n8x + 255) / 256), 256, 0, stream>>>(X, Xb, n8x, flags);
        long n8w1 = (long)HID * IN / 8;
        k_cvt8<<<(int)((n8w1 + 255) / 256), 256, 0, stream>>>(W1, W1c, n8w1, flags);
        long n8w2 = (long)OUT * HID / 8;
        k_cvt8<<<(int)((n8w2 + 255) / 256), 256, 0, stream>>>(W2, W2c, n8w2, flags);
    }

    k_count<<<(E + 255) / 256, 256, 0, stream>>>(ei, E, Nn, flags, deg);
    k_dinv<<<(Nn + 255) / 256, 256, 0, stream>>>(deg, dinv, Nn);
    k_scan<<<1, 1024, 0, stream>>>(deg, rowst, cursor, Nn);
    k_fill<<<(E + 255) / 256, 256, 0, stream>>>(ei, E, Nn, flags, cursor, csr);

    dim3 blk(256);
    auto ggrid = [&](int Ncols, int bn) { return dim3((Ncols + bn - 1) / bn, (Nn + 127) / 128); };
    const long zOff = 0, h2Off = (long)Nn * OUT, h4Off = (long)Nn * OUT * 2;

    // conv1: t1 = Xb @ W1^T ; h1 = S*t1 + b1
    gemm_nt<64><<<ggrid(HID, 64), blk, 0, stream>>>(Xb, W1c, t1, 0, nullptr, Nn, HID, IN, 0, flags);
    k_agg<512><<<(Nn * 64 + 255) / 256, blk, 0, stream>>>(t1, rowst, csr, dinv, bc1, h1, Nn);

    // conv2: t2 = h1 @ W2^T ; h2 = S*t2 + b2
    gemm_nt<64><<<ggrid(OUT, 64), blk, 0, stream>>>(h1, W2c, t2, 0, nullptr, Nn, OUT, HID, 0, flags);
    k_agg<128><<<(Nn * 16 + 255) / 256, blk, 0, stream>>>(t2, rowst, csr, dinv, bc2, h2ws, Nn);

    // z = h2 @ head1
    gemm_nt<64><<<ggrid(OUT, 64), blk, 0, stream>>>(h2ws, H1t, zws, 0, nullptr, Nn, OUT, OUT, 0, flags);

    // conv3 (agg-first, tied W2^T): g3 = S*z ; h3 = g3 @ W2 + b3
    k_agg<128><<<(Nn * 16 + 255) / 256, blk, 0, stream>>>(zws, rowst, csr, dinv, nullptr, t2, Nn);
    gemm_nt<64><<<ggrid(HID, 64), blk, 0, stream>>>(t2, W2t, h3, 0, bc3, Nn, HID, OUT, 0, flags);

    // conv4 (agg-first, tied W1^T): g4 = S*h3 ; h4 = g4 @ W1 + b4 -> d_out
    k_agg<512><<<(Nn * 64 + 255) / 256, blk, 0, stream>>>(h3, rowst, csr, dinv, nullptr, t1, Nn);
    gemm_nt<128><<<ggrid(IN, 128), blk, 0, stream>>>(t1, W1t, d_out, h4Off, bc4, Nn, IN, HID, 1, flags);

    // z, h2 -> d_out
    k_out<<<(2 * (int)h2Off + 255) / 256, blk, 0, stream>>>(zws, h2ws, d_out, (int)h2Off, flags);
}

// Round 4
// 564.001 us; speedup vs baseline: 2.0325x; 1.0153x over previous
//
#include <hip/hip_runtime.h>

typedef short   short8  __attribute__((ext_vector_type(8)));
typedef unsigned short ushort8 __attribute__((ext_vector_type(8)));
typedef float   floatx4 __attribute__((ext_vector_type(4)));

__device__ __forceinline__ float bf2f(unsigned short h) {
    unsigned int u = ((unsigned int)h) << 16;
    return __builtin_bit_cast(float, u);
}
__device__ __forceinline__ unsigned short f2bf(float f) {
    unsigned int u = __builtin_bit_cast(unsigned int, f);
    u += 0x7fffu + ((u >> 16) & 1u);   // round-to-nearest-even
    return (unsigned short)(u >> 16);
}

// ---------------- dtype detection ----------------
// flags[0] != 0  =>  float tensors delivered as fp32 (else bf16)
// flags[1] != 0  =>  edge_index delivered as int32 (else int64)

__global__ __launch_bounds__(256) void k_detect_f32(const unsigned short* __restrict__ X,
                                                    int nPairs, int* __restrict__ flags) {
    int i = blockIdx.x * 256 + threadIdx.x;
    if (i < nPairs) {
        unsigned short w = X[2 * i];
        if ((w & 0x7F80u) == 0x7F80u) atomicOr(&flags[0], 1);
    }
}

__global__ __launch_bounds__(256) void k_detect_i32(const int* __restrict__ ei,
                                                    int E, int* __restrict__ flags) {
    int i = blockIdx.x * 256 + threadIdx.x;
    if (i < E) {
        if (ei[2 * i + 1] != 0) atomicOr(&flags[1], 1);
    }
}

// ---------------- small converters ----------------

__global__ __launch_bounds__(256) void k_cvt_f32(const void* __restrict__ in,
                                                 float* __restrict__ out, int n,
                                                 const int* __restrict__ flags) {
    int i = blockIdx.x * 256 + threadIdx.x;
    if (i < n)
        out[i] = flags[0] ? ((const float*)in)[i] : bf2f(((const unsigned short*)in)[i]);
}

// bulk convert (or passthrough-copy) to bf16, 8 elems/thread, coalesced.
__global__ __launch_bounds__(256) void k_cvt8(const void* __restrict__ in,
                                              unsigned short* __restrict__ out,
                                              long n8, const int* __restrict__ flags) {
    long i = (long)blockIdx.x * 256 + threadIdx.x;
    if (i >= n8) return;
    ushort8 o;
    if (flags[0]) {
        const floatx4* f = (const floatx4*)in + i * 2;
        floatx4 a = f[0], b = f[1];
#pragma unroll
        for (int j = 0; j < 4; j++) { o[j] = f2bf(a[j]); o[4 + j] = f2bf(b[j]); }
    } else {
        o = *((const ushort8*)in + i);
    }
    *((ushort8*)out + i) = o;
}

__global__ __launch_bounds__(256) void k_tcvt(const void* __restrict__ in,
                                              unsigned short* __restrict__ out,
                                              int R, int C, const int* __restrict__ flags) {
    int idx = blockIdx.x * 256 + threadIdx.x;
    if (idx >= R * C) return;
    int r = idx / C, c = idx - r * C;
    unsigned short v = flags[0] ? f2bf(((const float*)in)[idx])
                                : ((const unsigned short*)in)[idx];
    out[(long)c * R + r] = v;
}

// ---------------- graph setup ----------------

__global__ __launch_bounds__(256) void k_count(const int* __restrict__ ei, int E, int n,
                                               const int* __restrict__ flags,
                                               int* __restrict__ deg) {
    int e = blockIdx.x * 256 + threadIdx.x;
    if (e >= E) return;
    int sh = (flags[1] == 0) ? 1 : 0;           // int64 -> stride-2 words
    int d = ei[(long)(E + e) << sh];
    if ((unsigned)d < (unsigned)n) atomicAdd(&deg[d], 1);
}

__global__ __launch_bounds__(256) void k_dinv(const int* __restrict__ deg,
                                              float* __restrict__ dinv, int n) {
    int i = blockIdx.x * 256 + threadIdx.x;
    if (i < n) dinv[i] = rsqrtf((float)(deg[i] + 1));  // +1 self-loop
}

__global__ __launch_bounds__(1024) void k_scan(const int* __restrict__ deg,
                                               int* __restrict__ row_start,
                                               int* __restrict__ cursor, int n) {
    __shared__ int sums[1024];
    int t = threadIdx.x;
    int CH = (n + 1 + 1023) / 1024;
    int base = t * CH;
    int s = 0;
    for (int i = 0; i < CH; i++) {
        int idx = base + i;
        if (idx < n) s += deg[idx];
    }
    sums[t] = s;
    __syncthreads();
    for (int off = 1; off < 1024; off <<= 1) {
        int v = (t >= off) ? sums[t - off] : 0;
        __syncthreads();
        if (t >= off) sums[t] += v;
        __syncthreads();
    }
    int run = (t > 0) ? sums[t - 1] : 0;
    for (int i = 0; i < CH; i++) {
        int idx = base + i;
        if (idx < n) {
            row_start[idx] = run;
            cursor[idx] = run;
            run += deg[idx];
        } else if (idx == n) {
            row_start[n] = run;
        }
    }
}

__global__ __launch_bounds__(256) void k_fill(const int* __restrict__ ei, int E, int n,
                                              const int* __restrict__ flags,
                                              int* __restrict__ cursor,
                                              int* __restrict__ csr) {
    int e = blockIdx.x * 256 + threadIdx.x;
    if (e >= E) return;
    int sh = (flags[1] == 0) ? 1 : 0;
    int s = ei[(long)e << sh];
    int d = ei[(long)(E + e) << sh];
    if ((unsigned)d >= (unsigned)n || (unsigned)s >= (unsigned)n) return;
    int p = atomicAdd(&cursor[d], 1);
    csr[p] = s;
}

// ---------------- NT GEMM: C[M,N] = A[M,K] * Bt[N,K]^T (+bias), fp32 acc ------
// A, Bt always bf16 (pre-converted). Output bf16, or fp32 if finalOut&&flags[0].
// Round-3 post-mortem: old loop issued tile-k loads and waited on them in the
// SAME k-step (vmcnt(0) at the LDS write) -> ~900cy HBM latency exposed per
// step, gemm at 13% MfmaUtil / 21% HBM. Fix = T3-minimum 2-phase: prefetch
// tile k+1 into named registers BEFORE the ds_read/MFMA phase of tile k, so
// the vmcnt wait lands after a full compute phase.
// NOTE (round-1): all acc/frag loops MUST be #pragma unroll'd (rule #20).

template <int BN>
__global__ __launch_bounds__(256, 3) void gemm_nt(const unsigned short* __restrict__ A,
                                               const unsigned short* __restrict__ Bt,
                                               void* __restrict__ Cv, long coff,
                                               const float* __restrict__ bias,
                                               int M, int N, int K, int finalOut,
                                               const int* __restrict__ flags) {
    constexpr int BM = 128, BK = 32, LDT = 40;  // pad 32->40: only free 2-way conflicts
    constexpr int JR = BN / 16;                 // B fragments per wave
    __shared__ unsigned short sA[BM * LDT];
    __shared__ unsigned short sB[BN * LDT];
    const bool of32 = finalOut && flags[0];
    const bool hasb = bias != nullptr;
    const int t = threadIdx.x;

    // bijective XCD-aware swizzle (contiguous chunk per XCD)
    const int GX = gridDim.x;
    const int nwg = GX * gridDim.y;
    const int orig = blockIdx.y * GX + blockIdx.x;
    const int q8 = nwg >> 3, r8 = nwg & 7;
    const int xcd = orig & 7, cidx = orig >> 3;
    const int swz = (xcd < r8 ? xcd * (q8 + 1) : r8 * (q8 + 1) + (xcd - r8) * q8) + cidx;
    const int m0 = (swz / GX) * BM;
    const int n0 = (swz % GX) * BN;

    const int w = t >> 6;
    const int lane = t & 63;
    const int id = lane & 15;
    const int q = lane >> 4;

    floatx4 acc[2][JR];
#pragma unroll
    for (int s = 0; s < 2; s++)
#pragma unroll
        for (int j = 0; j < JR; j++) acc[s][j] = (floatx4)0.0f;

    const int ar = t >> 2;          // 0..63
    const int ac = (t & 3) * 8;     // 0,8,16,24

    // per-thread source row pointers (row fixed; col walks by k0)
    const unsigned short* pa0 = A + (long)min(m0 + ar, M - 1) * K + ac;
    const unsigned short* pa1 = A + (long)min(m0 + ar + 64, M - 1) * K + ac;
    const unsigned short* pb0 = Bt + (long)min(n0 + ar, N - 1) * K + ac;
    const unsigned short* pb1 = Bt + (long)min(n0 + ar + ((BN == 128) ? 64 : 0), N - 1) * K + ac;

    // prefetch tile 0
    ushort8 va0 = *(const ushort8*)(pa0);
    ushort8 va1 = *(const ushort8*)(pa1);
    ushort8 vb0 = *(const ushort8*)(pb0);
    ushort8 vb1;
    if (BN == 128) vb1 = *(const ushort8*)(pb1);

    for (int k0 = 0; k0 < K; k0 += BK) {
        __syncthreads();               // previous compute done (no-op first iter)
        *(ushort8*)(sA + ar * LDT + ac) = va0;
        *(ushort8*)(sA + (ar + 64) * LDT + ac) = va1;
        *(ushort8*)(sB + ar * LDT + ac) = vb0;
        if (BN == 128)
            *(ushort8*)(sB + (ar + 64) * LDT + ac) = vb1;
        __syncthreads();

        // issue NEXT tile's loads now -- latency hides under the MFMA phase
        if (k0 + BK < K) {
            va0 = *(const ushort8*)(pa0 + k0 + BK);
            va1 = *(const ushort8*)(pa1 + k0 + BK);
            vb0 = *(const ushort8*)(pb0 + k0 + BK);
            if (BN == 128) vb1 = *(const ushort8*)(pb1 + k0 + BK);
        }

        short8 afrag[2], bfrag[JR];
#pragma unroll
        for (int s = 0; s < 2; s++)
            afrag[s] = *(const short8*)(sA + (32 * w + 16 * s + id) * LDT + q * 8);
#pragma unroll
        for (int j = 0; j < JR; j++)
            bfrag[j] = *(const short8*)(sB + (16 * j + id) * LDT + q * 8);
#pragma unroll
        for (int s = 0; s < 2; s++)
#pragma unroll
            for (int j = 0; j < JR; j++)
                acc[s][j] = __builtin_amdgcn_mfma_f32_16x16x32_bf16(
                    afrag[s], bfrag[j], acc[s][j], 0, 0, 0);
    }

#pragma unroll
    for (int s = 0; s < 2; s++)
#pragma unroll
        for (int j = 0; j < JR; j++) {
            int col = n0 + 16 * j + id;                        // C/D: col=lane&15
            float bv = hasb ? bias[col] : 0.0f;
#pragma unroll
            for (int r = 0; r < 4; r++) {
                int row = m0 + 32 * w + 16 * s + q * 4 + r;    // row=(lane>>4)*4+reg
                if (row < M) {
                    float v = acc[s][j][r] + bv;
                    if (of32) ((float*)Cv)[coff + (long)row * N + col] = v;
                    else ((unsigned short*)Cv)[coff + (long)row * N + col] = f2bf(v);
                }
            }
        }
}

// ------- aggregation: O[i] = dinv[i]*(sum_j T[csr_j]*dinv[csr_j] + T[i]*dinv[i]) + b

template <int D>
__global__ __launch_bounds__(256) void k_agg(const unsigned short* __restrict__ T,
                                             const int* __restrict__ rs,
                                             const int* __restrict__ csr,
                                             const float* __restrict__ dinv,
                                             const float* __restrict__ bias,
                                             unsigned short* __restrict__ O, int n) {
    constexpr int TPN = D / 8;
    constexpr int NPB = 256 / TPN;
    int lt = threadIdx.x % TPN;
    int node = blockIdx.x * NPB + threadIdx.x / TPN;
    if (node >= n) return;
    int off = lt * 8;
    float acc[8];
#pragma unroll
    for (int i = 0; i < 8; i++) acc[i] = 0.0f;
    int beg = rs[node], end = rs[node + 1];
    for (int j = beg; j < end; j++) {
        int s = csr[j];
        if ((unsigned)s >= (unsigned)n) continue;
        float wgt = dinv[s];
        ushort8 v = *(const ushort8*)(T + (long)s * D + off);
#pragma unroll
        for (int i = 0; i < 8; i++) acc[i] += wgt * bf2f(v[i]);
    }
    float di = dinv[node];
    ushort8 sv = *(const ushort8*)(T + (long)node * D + off);
    ushort8 o;
#pragma unroll
    for (int i = 0; i < 8; i++) {
        float r = di * (acc[i] + di * bf2f(sv[i])) + (bias ? bias[off + i] : 0.0f);
        o[i] = f2bf(r);
    }
    *(ushort8*)(O + (long)node * D + off) = o;
}

// ---------------- final copy of z, h2 into d_out ----------------

__global__ __launch_bounds__(256) void k_out(const unsigned short* __restrict__ z,
                                             const unsigned short* __restrict__ h2,
                                             void* __restrict__ out, int nOut,
                                             const int* __restrict__ flags) {
    int i = blockIdx.x * 256 + threadIdx.x;
    if (i >= 2 * nOut) return;
    unsigned short v = (i < nOut) ? z[i] : h2[i - nOut];
    if (flags[0]) ((float*)out)[i] = bf2f(v);
    else ((unsigned short*)out)[i] = v;
}

// ---------------- launch ----------------

extern "C" void kernel_launch(void* const* d_in, const int* in_sizes, int n_in,
                              void* d_out, int out_size, void* d_ws, size_t ws_size,
                              hipStream_t stream) {
    const int IN  = in_sizes[7];           // 1024
    const int HID = in_sizes[3];           // 512
    const int OUT = in_sizes[5];           // 128
    const int Nn  = in_sizes[0] / IN;      // 20000
    const int E   = in_sizes[1] / 2;       // 160000

    const void* X   = d_in[0];
    const int*  ei  = (const int*)d_in[1];
    const void* W1  = d_in[2];
    const void* b1  = d_in[3];
    const void* W2  = d_in[4];
    const void* b2  = d_in[5];
    const void* b3  = d_in[6];
    const void* b4  = d_in[7];
    const void* Hd1 = d_in[8];

    char* base = (char*)d_ws;
    size_t o = 0;
    auto carve = [&](size_t bytes) -> char* {
        char* p = base + o;
        o = (o + bytes + 255) & ~(size_t)255;
        return p;
    };
    int*   flags  = (int*)carve(2 * 4);
    int*   deg    = (int*)carve((size_t)Nn * 4);
    int*   rowst  = (int*)carve((size_t)(Nn + 1) * 4);
    int*   cursor = (int*)carve((size_t)Nn * 4);
    float* dinv   = (float*)carve((size_t)Nn * 4);
    int*   csr    = (int*)carve((size_t)E * 4);
    float* biasf  = (float*)carve((size_t)(HID + OUT + HID + IN) * 4);
    float* bc1 = biasf, *bc2 = biasf + HID, *bc3 = biasf + HID + OUT,
         *bc4 = biasf + HID + OUT + HID;
    unsigned short* W1t  = (unsigned short*)carve((size_t)IN * HID * 2);
    unsigned short* W2t  = (unsigned short*)carve((size_t)HID * OUT * 2);
    unsigned short* H1t  = (unsigned short*)carve((size_t)OUT * OUT * 2);
    unsigned short* W1c  = (unsigned short*)carve((size_t)HID * IN * 2);
    unsigned short* W2c  = (unsigned short*)carve((size_t)OUT * HID * 2);
    unsigned short* Xb   = (unsigned short*)carve((size_t)Nn * IN * 2);
    unsigned short* t1   = (unsigned short*)carve((size_t)Nn * HID * 2); // also g4
    unsigned short* h1   = (unsigned short*)carve((size_t)Nn * HID * 2);
    unsigned short* h3   = (unsigned short*)carve((size_t)Nn * HID * 2);
    unsigned short* t2   = (unsigned short*)carve((size_t)Nn * OUT * 2); // also g3
    unsigned short* h2ws = (unsigned short*)carve((size_t)Nn * OUT * 2);
    unsigned short* zws  = (unsigned short*)carve((size_t)Nn * OUT * 2);

    // --- detection + graph setup ---
    hipMemsetAsync(flags, 0, 8, stream);
    hipMemsetAsync(deg, 0, (size_t)Nn * 4, stream);
    int nPairs = 1 << 20;
    k_detect_f32<<<(nPairs + 255) / 256, 256, 0, stream>>>((const unsigned short*)X, nPairs, flags);
    k_detect_i32<<<(E + 255) / 256, 256, 0, stream>>>(ei, E, flags);

    k_cvt_f32<<<(HID + 255) / 256, 256, 0, stream>>>(b1, bc1, HID, flags);
    k_cvt_f32<<<(OUT + 255) / 256, 256, 0, stream>>>(b2, bc2, OUT, flags);
    k_cvt_f32<<<(HID + 255) / 256, 256, 0, stream>>>(b3, bc3, HID, flags);
    k_cvt_f32<<<(IN + 255) / 256, 256, 0, stream>>>(b4, bc4, IN, flags);

    k_tcvt<<<(HID * IN + 255) / 256, 256, 0, stream>>>(W1, W1t, HID, IN, flags);
    k_tcvt<<<(OUT * HID + 255) / 256, 256, 0, stream>>>(W2, W2t, OUT, HID, flags);
    k_tcvt<<<(OUT * OUT + 255) / 256, 256, 0, stream>>>(Hd1, H1t, OUT, OUT, flags);

    // bf16 copies of X, W1, W2 for the GEMMs (pure-bf16 load path)
    {
        long n8x = (long)Nn * IN / 8;
        k_cvt8<<<(int)((n8x + 255) / 256), 256, 0, stream>>>(X, Xb, n8x, flags);
        long n8w1 = (long)HID * IN / 8;
        k_cvt8<<<(int)((n8w1 + 255) / 256), 256, 0, stream>>>(W1, W1c, n8w1, flags);
        long n8w2 = (long)OUT * HID / 8;
        k_cvt8<<<(int)((n8w2 + 255) / 256), 256, 0, stream>>>(W2, W2c, n8w2, flags);
    }

    k_count<<<(E + 255) / 256, 256, 0, stream>>>(ei, E, Nn, flags, deg);
    k_dinv<<<(Nn + 255) / 256, 256, 0, stream>>>(deg, dinv, Nn);
    k_scan<<<1, 1024, 0, stream>>>(deg, rowst, cursor, Nn);
    k_fill<<<(E + 255) / 256, 256, 0, stream>>>(ei, E, Nn, flags, cursor, csr);

    dim3 blk(256);
    auto ggrid = [&](int Ncols, int bn) { return dim3((Ncols + bn - 1) / bn, (Nn + 127) / 128); };
    const long zOff = 0, h2Off = (long)Nn * OUT, h4Off = (long)Nn * OUT * 2;

    // conv1: t1 = Xb @ W1^T ; h1 = S*t1 + b1
    gemm_nt<64><<<ggrid(HID, 64), blk, 0, stream>>>(Xb, W1c, t1, 0, nullptr, Nn, HID, IN, 0, flags);
    k_agg<512><<<(Nn * 64 + 255) / 256, blk, 0, stream>>>(t1, rowst, csr, dinv, bc1, h1, Nn);

    // conv2: t2 = h1 @ W2^T ; h2 = S*t2 + b2
    gemm_nt<64><<<ggrid(OUT, 64), blk, 0, stream>>>(h1, W2c, t2, 0, nullptr, Nn, OUT, HID, 0, flags);
    k_agg<128><<<(Nn * 16 + 255) / 256, blk, 0, stream>>>(t2, rowst, csr, dinv, bc2, h2ws, Nn);

    // z = h2 @ head1
    gemm_nt<64><<<ggrid(OUT, 64), blk, 0, stream>>>(h2ws, H1t, zws, 0, nullptr, Nn, OUT, OUT, 0, flags);

    // conv3 (agg-first, tied W2^T): g3 = S*z ; h3 = g3 @ W2 + b3
    k_agg<128><<<(Nn * 16 + 255) / 256, blk, 0, stream>>>(zws, rowst, csr, dinv, nullptr, t2, Nn);
    gemm_nt<64><<<ggrid(HID, 64), blk, 0, stream>>>(t2, W2t, h3, 0, bc3, Nn, HID, OUT, 0, flags);

    // conv4 (agg-first, tied W1^T): g4 = S*h3 ; h4 = g4 @ W1 + b4 -> d_out
    k_agg<512><<<(Nn * 64 + 255) / 256, blk, 0, stream>>>(h3, rowst, csr, dinv, nullptr, t1, Nn);
    gemm_nt<128><<<ggrid(IN, 128), blk, 0, stream>>>(t1, W1t, d_out, h4Off, bc4, Nn, IN, HID, 1, flags);

    // z, h2 -> d_out
    k_out<<<(2 * (int)h2Off + 255) / 256, blk, 0, stream>>>(zws, h2ws, d_out, (int)h2Off, flags);
}

// Round 5
// 545.966 us; speedup vs baseline: 2.0997x; 1.0330x over previous
//
#include <hip/hip_runtime.h>

typedef short   short8  __attribute__((ext_vector_type(8)));
typedef unsigned short ushort8 __attribute__((ext_vector_type(8)));
typedef unsigned short bf4     __attribute__((ext_vector_type(4)));
typedef float   floatx4 __attribute__((ext_vector_type(4)));

__device__ __forceinline__ float bf2f(unsigned short h) {
    unsigned int u = ((unsigned int)h) << 16;
    return __builtin_bit_cast(float, u);
}
__device__ __forceinline__ unsigned short f2bf(float f) {
    unsigned int u = __builtin_bit_cast(unsigned int, f);
    u += 0x7fffu + ((u >> 16) & 1u);   // round-to-nearest-even
    return (unsigned short)(u >> 16);
}

// ---------------- dtype detection ----------------
// flags[0] != 0  =>  float tensors delivered as fp32 (else bf16)
// flags[1] != 0  =>  edge_index delivered as int32 (else int64)

__global__ __launch_bounds__(256) void k_detect_f32(const unsigned short* __restrict__ X,
                                                    int nPairs, int* __restrict__ flags) {
    int i = blockIdx.x * 256 + threadIdx.x;
    if (i < nPairs) {
        unsigned short w = X[2 * i];
        if ((w & 0x7F80u) == 0x7F80u) atomicOr(&flags[0], 1);
    }
}

__global__ __launch_bounds__(256) void k_detect_i32(const int* __restrict__ ei,
                                                    int E, int* __restrict__ flags) {
    int i = blockIdx.x * 256 + threadIdx.x;
    if (i < E) {
        if (ei[2 * i + 1] != 0) atomicOr(&flags[1], 1);
    }
}

// ---------------- small converters ----------------

__global__ __launch_bounds__(256) void k_cvt_f32(const void* __restrict__ in,
                                                 float* __restrict__ out, int n,
                                                 const int* __restrict__ flags) {
    int i = blockIdx.x * 256 + threadIdx.x;
    if (i < n)
        out[i] = flags[0] ? ((const float*)in)[i] : bf2f(((const unsigned short*)in)[i]);
}

// bulk convert (or passthrough-copy) to bf16, 8 elems/thread, coalesced.
__global__ __launch_bounds__(256) void k_cvt8(const void* __restrict__ in,
                                              unsigned short* __restrict__ out,
                                              long n8, const int* __restrict__ flags) {
    long i = (long)blockIdx.x * 256 + threadIdx.x;
    if (i >= n8) return;
    ushort8 o;
    if (flags[0]) {
        const floatx4* f = (const floatx4*)in + i * 2;
        floatx4 a = f[0], b = f[1];
#pragma unroll
        for (int j = 0; j < 4; j++) { o[j] = f2bf(a[j]); o[4 + j] = f2bf(b[j]); }
    } else {
        o = *((const ushort8*)in + i);
    }
    *((ushort8*)out + i) = o;
}

__global__ __launch_bounds__(256) void k_tcvt(const void* __restrict__ in,
                                              unsigned short* __restrict__ out,
                                              int R, int C, const int* __restrict__ flags) {
    int idx = blockIdx.x * 256 + threadIdx.x;
    if (idx >= R * C) return;
    int r = idx / C, c = idx - r * C;
    unsigned short v = flags[0] ? f2bf(((const float*)in)[idx])
                                : ((const unsigned short*)in)[idx];
    out[(long)c * R + r] = v;
}

// ---------------- graph setup ----------------

__global__ __launch_bounds__(256) void k_count(const int* __restrict__ ei, int E, int n,
                                               const int* __restrict__ flags,
                                               int* __restrict__ deg) {
    int e = blockIdx.x * 256 + threadIdx.x;
    if (e >= E) return;
    int sh = (flags[1] == 0) ? 1 : 0;           // int64 -> stride-2 words
    int d = ei[(long)(E + e) << sh];
    if ((unsigned)d < (unsigned)n) atomicAdd(&deg[d], 1);
}

__global__ __launch_bounds__(256) void k_dinv(const int* __restrict__ deg,
                                              float* __restrict__ dinv, int n) {
    int i = blockIdx.x * 256 + threadIdx.x;
    if (i < n) dinv[i] = rsqrtf((float)(deg[i] + 1));  // +1 self-loop
}

__global__ __launch_bounds__(1024) void k_scan(const int* __restrict__ deg,
                                               int* __restrict__ row_start,
                                               int* __restrict__ cursor, int n) {
    __shared__ int sums[1024];
    int t = threadIdx.x;
    int CH = (n + 1 + 1023) / 1024;
    int base = t * CH;
    int s = 0;
    for (int i = 0; i < CH; i++) {
        int idx = base + i;
        if (idx < n) s += deg[idx];
    }
    sums[t] = s;
    __syncthreads();
    for (int off = 1; off < 1024; off <<= 1) {
        int v = (t >= off) ? sums[t - off] : 0;
        __syncthreads();
        if (t >= off) sums[t] += v;
        __syncthreads();
    }
    int run = (t > 0) ? sums[t - 1] : 0;
    for (int i = 0; i < CH; i++) {
        int idx = base + i;
        if (idx < n) {
            row_start[idx] = run;
            cursor[idx] = run;
            run += deg[idx];
        } else if (idx == n) {
            row_start[n] = run;
        }
    }
}

__global__ __launch_bounds__(256) void k_fill(const int* __restrict__ ei, int E, int n,
                                              const int* __restrict__ flags,
                                              int* __restrict__ cursor,
                                              int* __restrict__ csr) {
    int e = blockIdx.x * 256 + threadIdx.x;
    if (e >= E) return;
    int sh = (flags[1] == 0) ? 1 : 0;
    int s = ei[(long)e << sh];
    int d = ei[(long)(E + e) << sh];
    if ((unsigned)d >= (unsigned)n || (unsigned)s >= (unsigned)n) return;
    int p = atomicAdd(&cursor[d], 1);
    csr[p] = s;
}

// ---------------- NT GEMM: C[M,N] = A[M,K] * Bt[N,K]^T (+bias), fp32 acc ------
// A, Bt bf16 (pre-converted). Output bf16, or fp32 if finalOut&&flags[0].
// Round-4 post-mortem: guarded manual prefetch + 2 barriers/step regressed
// conv4 (74us, MfmaUtil 11%). This version:
//  * LDS DOUBLE-BUFFER, ONE barrier per K-step (T3-minimum): prefetch k+1 at
//    phase start -> ds_read+MFMA covers latency -> ds_write other buffer.
//  * SWAPPED-OPERAND MFMA (mfma(b,a,acc)): D rows=m(lane-fixed), cols=4
//    consecutive n per lane -> float4/ushort4 epilogue stores (was 4x scalar).
//  * BM=64 variant for N=128 gemms (grid 314 -> 626 blocks).
// NOTE (round-1): all acc/frag loops MUST be #pragma unroll'd (rule #20).

template <int BM, int BN>
__global__ __launch_bounds__(256, (BN == 128 ? 3 : 4))
void gemm_nt(const unsigned short* __restrict__ A,
             const unsigned short* __restrict__ Bt,
             void* __restrict__ Cv, long coff,
             const float* __restrict__ bias,
             int M, int N, int K, int finalOut,
             const int* __restrict__ flags) {
    constexpr int BK = 32, LDT = 40;   // pad 32->40: only free 2-way conflicts
    constexpr int JR = BN / 16;        // B fragments per wave
    constexpr int SM = BM / 64;        // A subtiles per wave (1 or 2)
    __shared__ unsigned short sA[2][BM * LDT];
    __shared__ unsigned short sB[2][BN * LDT];
    const bool of32 = finalOut && flags[0];
    const bool hasb = bias != nullptr;
    const int t = threadIdx.x;

    // bijective XCD-aware swizzle (contiguous chunk per XCD)
    const int GX = gridDim.x;
    const int nwg = GX * gridDim.y;
    const int orig = blockIdx.y * GX + blockIdx.x;
    const int q8 = nwg >> 3, r8 = nwg & 7;
    const int xcd = orig & 7, cidx = orig >> 3;
    const int swz = (xcd < r8 ? xcd * (q8 + 1) : r8 * (q8 + 1) + (xcd - r8) * q8) + cidx;
    const int m0 = (swz / GX) * BM;
    const int n0 = (swz % GX) * BN;

    const int w = t >> 6;
    const int lane = t & 63;
    const int id = lane & 15;
    const int q = lane >> 4;

    floatx4 acc[SM][JR];
#pragma unroll
    for (int s = 0; s < SM; s++)
#pragma unroll
        for (int j = 0; j < JR; j++) acc[s][j] = (floatx4)0.0f;

    const int ar = t >> 2;          // 0..63
    const int ac = (t & 3) * 8;     // 0,8,16,24

    // per-thread source row pointers (row fixed; col walks by k0)
    const unsigned short* pa0 = A + (long)min(m0 + ar, M - 1) * K + ac;
    const unsigned short* pa1 = (SM == 2)
        ? A + (long)min(m0 + ar + 64, M - 1) * K + ac : pa0;
    const unsigned short* pb0 = Bt + (long)min(n0 + ar, N - 1) * K + ac;
    const unsigned short* pb1 = (JR == 8)
        ? Bt + (long)min(n0 + ar + 64, N - 1) * K + ac : pb0;

    // prologue: stage tile 0 into buffer 0
    {
        ushort8 va0 = *(const ushort8*)(pa0);
        ushort8 va1; if (SM == 2) va1 = *(const ushort8*)(pa1);
        ushort8 vb0 = *(const ushort8*)(pb0);
        ushort8 vb1; if (JR == 8) vb1 = *(const ushort8*)(pb1);
        *(ushort8*)(sA[0] + ar * LDT + ac) = va0;
        if (SM == 2) *(ushort8*)(sA[0] + (ar + 64) * LDT + ac) = va1;
        *(ushort8*)(sB[0] + ar * LDT + ac) = vb0;
        if (JR == 8) *(ushort8*)(sB[0] + (ar + 64) * LDT + ac) = vb1;
        __syncthreads();
    }

    auto STEP = [&](int k0, const unsigned short* sAr, const unsigned short* sBr,
                    unsigned short* sAw, unsigned short* sBw, bool last) {
        ushort8 na0, na1, nb0, nb1;
        if (!last) {                       // issue next tile's loads FIRST
            na0 = *(const ushort8*)(pa0 + k0 + BK);
            if (SM == 2) na1 = *(const ushort8*)(pa1 + k0 + BK);
            nb0 = *(const ushort8*)(pb0 + k0 + BK);
            if (JR == 8) nb1 = *(const ushort8*)(pb1 + k0 + BK);
        }
        short8 afrag[SM], bfrag[JR];
#pragma unroll
        for (int s = 0; s < SM; s++)
            afrag[s] = *(const short8*)(sAr + ((SM == 2 ? 32 * w + 16 * s : 16 * w) + id) * LDT + q * 8);
#pragma unroll
        for (int j = 0; j < JR; j++)
            bfrag[j] = *(const short8*)(sBr + (16 * j + id) * LDT + q * 8);
#pragma unroll
        for (int s = 0; s < SM; s++)
#pragma unroll
            for (int j = 0; j < JR; j++)
                acc[s][j] = __builtin_amdgcn_mfma_f32_16x16x32_bf16(
                    bfrag[j], afrag[s], acc[s][j], 0, 0, 0);   // SWAPPED operands
        if (!last) {
            *(ushort8*)(sAw + ar * LDT + ac) = na0;
            if (SM == 2) *(ushort8*)(sAw + (ar + 64) * LDT + ac) = na1;
            *(ushort8*)(sBw + ar * LDT + ac) = nb0;
            if (JR == 8) *(ushort8*)(sBw + (ar + 64) * LDT + ac) = nb1;
            __syncthreads();               // single barrier per K-step
        }
    };

    for (int k0 = 0; k0 < K; k0 += 2 * BK) {     // K/BK always even here
        STEP(k0, sA[0], sB[0], sA[1], sB[1], false);
        STEP(k0 + BK, sA[1], sB[1], sA[0], sB[0], k0 + 2 * BK >= K);
    }

    // epilogue: swapped D layout -> lane holds row m = ...+id (fixed),
    // 4 consecutive cols n = n0+16j+4q+r  => vector stores
#pragma unroll
    for (int s = 0; s < SM; s++) {
        const int row = m0 + (SM == 2 ? 32 * w + 16 * s : 16 * w) + id;
        if (row < M) {
#pragma unroll
            for (int j = 0; j < JR; j++) {
                const int colb = n0 + 16 * j + 4 * q;
                floatx4 v = acc[s][j];
                if (hasb) v = v + *(const floatx4*)(bias + colb);
                const long off = coff + (long)row * N + colb;
                if (of32) {
                    *(floatx4*)((float*)Cv + off) = v;
                } else {
                    bf4 o;
#pragma unroll
                    for (int r = 0; r < 4; r++) o[r] = f2bf(v[r]);
                    *(bf4*)((unsigned short*)Cv + off) = o;
                }
            }
        }
    }
}

// ------- aggregation: O[i] = dinv[i]*(sum_j T[csr_j]*dinv[csr_j] + T[i]*dinv[i]) + b

template <int D>
__global__ __launch_bounds__(256) void k_agg(const unsigned short* __restrict__ T,
                                             const int* __restrict__ rs,
                                             const int* __restrict__ csr,
                                             const float* __restrict__ dinv,
                                             const float* __restrict__ bias,
                                             unsigned short* __restrict__ O, int n) {
    constexpr int TPN = D / 8;
    constexpr int NPB = 256 / TPN;
    int lt = threadIdx.x % TPN;
    int node = blockIdx.x * NPB + threadIdx.x / TPN;
    if (node >= n) return;
    int off = lt * 8;
    float acc[8];
#pragma unroll
    for (int i = 0; i < 8; i++) acc[i] = 0.0f;
    int beg = rs[node], end = rs[node + 1];
    for (int j = beg; j < end; j++) {
        int s = csr[j];
        if ((unsigned)s >= (unsigned)n) continue;
        float wgt = dinv[s];
        ushort8 v = *(const ushort8*)(T + (long)s * D + off);
#pragma unroll
        for (int i = 0; i < 8; i++) acc[i] += wgt * bf2f(v[i]);
    }
    float di = dinv[node];
    ushort8 sv = *(const ushort8*)(T + (long)node * D + off);
    ushort8 o;
#pragma unroll
    for (int i = 0; i < 8; i++) {
        float r = di * (acc[i] + di * bf2f(sv[i])) + (bias ? bias[off + i] : 0.0f);
        o[i] = f2bf(r);
    }
    *(ushort8*)(O + (long)node * D + off) = o;
}

// ---------------- final copy of z, h2 into d_out ----------------

__global__ __launch_bounds__(256) void k_out(const unsigned short* __restrict__ z,
                                             const unsigned short* __restrict__ h2,
                                             void* __restrict__ out, int nOut,
                                             const int* __restrict__ flags) {
    int i = blockIdx.x * 256 + threadIdx.x;
    if (i >= 2 * nOut) return;
    unsigned short v = (i < nOut) ? z[i] : h2[i - nOut];
    if (flags[0]) ((float*)out)[i] = bf2f(v);
    else ((unsigned short*)out)[i] = v;
}

// ---------------- launch ----------------

extern "C" void kernel_launch(void* const* d_in, const int* in_sizes, int n_in,
                              void* d_out, int out_size, void* d_ws, size_t ws_size,
                              hipStream_t stream) {
    const int IN  = in_sizes[7];           // 1024
    const int HID = in_sizes[3];           // 512
    const int OUT = in_sizes[5];           // 128
    const int Nn  = in_sizes[0] / IN;      // 20000
    const int E   = in_sizes[1] / 2;       // 160000

    const void* X   = d_in[0];
    const int*  ei  = (const int*)d_in[1];
    const void* W1  = d_in[2];
    const void* b1  = d_in[3];
    const void* W2  = d_in[4];
    const void* b2  = d_in[5];
    const void* b3  = d_in[6];
    const void* b4  = d_in[7];
    const void* Hd1 = d_in[8];

    char* base = (char*)d_ws;
    size_t o = 0;
    auto carve = [&](size_t bytes) -> char* {
        char* p = base + o;
        o = (o + bytes + 255) & ~(size_t)255;
        return p;
    };
    int*   flags  = (int*)carve(2 * 4);
    int*   deg    = (int*)carve((size_t)Nn * 4);
    int*   rowst  = (int*)carve((size_t)(Nn + 1) * 4);
    int*   cursor = (int*)carve((size_t)Nn * 4);
    float* dinv   = (float*)carve((size_t)Nn * 4);
    int*   csr    = (int*)carve((size_t)E * 4);
    float* biasf  = (float*)carve((size_t)(HID + OUT + HID + IN) * 4);
    float* bc1 = biasf, *bc2 = biasf + HID, *bc3 = biasf + HID + OUT,
         *bc4 = biasf + HID + OUT + HID;
    unsigned short* W1t  = (unsigned short*)carve((size_t)IN * HID * 2);
    unsigned short* W2t  = (unsigned short*)carve((size_t)HID * OUT * 2);
    unsigned short* H1t  = (unsigned short*)carve((size_t)OUT * OUT * 2);
    unsigned short* W1c  = (unsigned short*)carve((size_t)HID * IN * 2);
    unsigned short* W2c  = (unsigned short*)carve((size_t)OUT * HID * 2);
    unsigned short* Xb   = (unsigned short*)carve((size_t)Nn * IN * 2);
    unsigned short* t1   = (unsigned short*)carve((size_t)Nn * HID * 2); // also g4
    unsigned short* h1   = (unsigned short*)carve((size_t)Nn * HID * 2);
    unsigned short* h3   = (unsigned short*)carve((size_t)Nn * HID * 2);
    unsigned short* t2   = (unsigned short*)carve((size_t)Nn * OUT * 2); // also g3
    unsigned short* h2ws = (unsigned short*)carve((size_t)Nn * OUT * 2);
    unsigned short* zws  = (unsigned short*)carve((size_t)Nn * OUT * 2);

    // --- detection + graph setup ---
    hipMemsetAsync(flags, 0, 8, stream);
    hipMemsetAsync(deg, 0, (size_t)Nn * 4, stream);
    int nPairs = 1 << 20;
    k_detect_f32<<<(nPairs + 255) / 256, 256, 0, stream>>>((const unsigned short*)X, nPairs, flags);
    k_detect_i32<<<(E + 255) / 256, 256, 0, stream>>>(ei, E, flags);

    k_cvt_f32<<<(HID + 255) / 256, 256, 0, stream>>>(b1, bc1, HID, flags);
    k_cvt_f32<<<(OUT + 255) / 256, 256, 0, stream>>>(b2, bc2, OUT, flags);
    k_cvt_f32<<<(HID + 255) / 256, 256, 0, stream>>>(b3, bc3, HID, flags);
    k_cvt_f32<<<(IN + 255) / 256, 256, 0, stream>>>(b4, bc4, IN, flags);

    k_tcvt<<<(HID * IN + 255) / 256, 256, 0, stream>>>(W1, W1t, HID, IN, flags);
    k_tcvt<<<(OUT * HID + 255) / 256, 256, 0, stream>>>(W2, W2t, OUT, HID, flags);
    k_tcvt<<<(OUT * OUT + 255) / 256, 256, 0, stream>>>(Hd1, H1t, OUT, OUT, flags);

    // bf16 copies of X, W1, W2 for the GEMMs (pure-bf16 load path)
    {
        long n8x = (long)Nn * IN / 8;
        k_cvt8<<<(int)((n8x + 255) / 256), 256, 0, stream>>>(X, Xb, n8x, flags);
        long n8w1 = (long)HID * IN / 8;
        k_cvt8<<<(int)((n8w1 + 255) / 256), 256, 0, stream>>>(W1, W1c, n8w1, flags);
        long n8w2 = (long)OUT * HID / 8;
        k_cvt8<<<(int)((n8w2 + 255) / 256), 256, 0, stream>>>(W2, W2c, n8w2, flags);
    }

    k_count<<<(E + 255) / 256, 256, 0, stream>>>(ei, E, Nn, flags, deg);
    k_dinv<<<(Nn + 255) / 256, 256, 0, stream>>>(deg, dinv, Nn);
    k_scan<<<1, 1024, 0, stream>>>(deg, rowst, cursor, Nn);
    k_fill<<<(E + 255) / 256, 256, 0, stream>>>(ei, E, Nn, flags, cursor, csr);

    dim3 blk(256);
    auto ggrid = [&](int Ncols, int bn, int bm) {
        return dim3((Ncols + bn - 1) / bn, (Nn + bm - 1) / bm);
    };
    const long h2Off = (long)Nn * OUT, h4Off = (long)Nn * OUT * 2;

    // conv1: t1 = Xb @ W1^T ; h1 = S*t1 + b1
    gemm_nt<128, 64><<<ggrid(HID, 64, 128), blk, 0, stream>>>(Xb, W1c, t1, 0, nullptr, Nn, HID, IN, 0, flags);
    k_agg<512><<<(Nn * 64 + 255) / 256, blk, 0, stream>>>(t1, rowst, csr, dinv, bc1, h1, Nn);

    // conv2: t2 = h1 @ W2^T ; h2 = S*t2 + b2
    gemm_nt<64, 64><<<ggrid(OUT, 64, 64), blk, 0, stream>>>(h1, W2c, t2, 0, nullptr, Nn, OUT, HID, 0, flags);
    k_agg<128><<<(Nn * 16 + 255) / 256, blk, 0, stream>>>(t2, rowst, csr, dinv, bc2, h2ws, Nn);

    // z = h2 @ head1
    gemm_nt<64, 64><<<ggrid(OUT, 64, 64), blk, 0, stream>>>(h2ws, H1t, zws, 0, nullptr, Nn, OUT, OUT, 0, flags);

    // conv3 (agg-first, tied W2^T): g3 = S*z ; h3 = g3 @ W2 + b3
    k_agg<128><<<(Nn * 16 + 255) / 256, blk, 0, stream>>>(zws, rowst, csr, dinv, nullptr, t2, Nn);
    gemm_nt<128, 64><<<ggrid(HID, 64, 128), blk, 0, stream>>>(t2, W2t, h3, 0, bc3, Nn, HID, OUT, 0, flags);

    // conv4 (agg-first, tied W1^T): g4 = S*h3 ; h4 = g4 @ W1 + b4 -> d_out
    k_agg<512><<<(Nn * 64 + 255) / 256, blk, 0, stream>>>(h3, rowst, csr, dinv, nullptr, t1, Nn);
    gemm_nt<128, 128><<<ggrid(IN, 128, 128), blk, 0, stream>>>(t1, W1t, d_out, h4Off, bc4, Nn, IN, HID, 1, flags);

    // z, h2 -> d_out
    k_out<<<(2 * (int)h2Off + 255) / 256, blk, 0, stream>>>(zws, h2ws, d_out, (int)h2Off, flags);
}